// Round 5
// baseline (380.927 us; speedup 1.0000x reference)
//
#include <hip/hip_runtime.h>
#include <hip/hip_bf16.h>
#include <math.h>
#include <stdint.h>

typedef unsigned short u16;
typedef unsigned int   u32;
typedef __attribute__((ext_vector_type(8))) short bf16x8;
typedef __attribute__((ext_vector_type(4))) float f32x4;

#define EDIM 256
#define HDIM 128
#define TLEN 128
#define NUTT 1024
#define UU   32
#define NBU  8          // utterances per scan block (256 blocks = 1/CU)

#define WS_FLAG 0
#define WS_LENS 64
#define WS_TAB  4608
#define WS_COPY 8192
#define WS_OF   18874368LL
#define WS_OB   52428800LL

#define MFMA16(a, b, c) __builtin_amdgcn_mfma_f32_16x16x32_bf16((a), (b), (c), 0, 0, 0)
#define SOUT(u, s, j) ((u) * 1096 + (s) * 136 + (j))

__constant__ int G_SZ[18] = {7680000, 98304, 49152, 384, 384, 98304, 49152, 384, 384,
                             65536, 256, 65536, 65536, 256, 65536, 256, 65536, 256};

__device__ __forceinline__ float b2f(u16 b) {
    u32 u = ((u32)b) << 16; float f; __builtin_memcpy(&f, &u, 4); return f;
}
__device__ __forceinline__ u16 f2b(float f) {   // RNE manual (cold paths)
    u32 u; __builtin_memcpy(&u, &f, 4);
    u32 r = u + 0x7FFFu + ((u >> 16) & 1u);
    return (u16)(r >> 16);
}
__device__ __forceinline__ u16 f2b_hw(float f) {
    __hip_bfloat16 h = __float2bfloat16(f);
    u16 v; __builtin_memcpy(&v, &h, 2); return v;
}
__device__ __forceinline__ float fsigmoid(float x) { return 1.0f / (1.0f + __expf(-x)); }
__device__ __forceinline__ float ftanh(float x) { return 1.0f - 2.0f / (__expf(2.0f * x) + 1.0f); }

// lane^32 exchange. R3/R4 tried v_permlane32_swap_b32 inline-asm; BOTH
// select directions failed correctness (absmax 4.2e-2 / 1.58e-1) — the
// two-operand semantics are allocation-dependent in a way we cannot
// verify headlessly. REVERTED to __shfl_xor(.,32): R2-proven correct
// (absmax 6.1e-4). Do not reintroduce permlane here without disasm.
__device__ __forceinline__ float xor32f(float v) { return __shfl_xor(v, 32); }

// -------------------------------------------------------------------------
// k_convert: merged detect+convert+lens (one launch instead of two).
// -------------------------------------------------------------------------
__global__ __launch_bounds__(256)
void k_convert(void* ws,
               const int* __restrict__ d_ids, const int* __restrict__ utt_len,
               const void* a0, const void* a1, const void* a2, const void* a3,
               const void* a4, const void* a5, const void* a6, const void* a7,
               const void* a8, const void* a9, const void* a10, const void* a11,
               const void* a12, const void* a13, const void* a14, const void* a15,
               const void* a16, const void* a17) {
    __shared__ int scnt[4];
    const int tid = threadIdx.x, lane = tid & 63, wid = tid >> 6;
    const u16* p = (const u16*)a0;
    int cnt = 0;
#pragma unroll 8
    for (int i = tid; i < 16384; i += 256)
        cnt += ((p[i] & 0x7F80) == 0x7F80) ? 1 : 0;
#pragma unroll
    for (int o = 32; o > 0; o >>= 1) cnt += __shfl_down(cnt, o);
    if (lane == 0) scnt[wid] = cnt;
    __syncthreads();
    const int flag = (scnt[0] + scnt[1] + scnt[2] + scnt[3] > 0) ? 1 : 0;

    if (blockIdx.x == 0) {
        if (tid == 0) {
            const void* orig[18] = {a0,a1,a2,a3,a4,a5,a6,a7,a8,a9,a10,a11,a12,a13,a14,a15,a16,a17};
            *(int*)((char*)ws + WS_FLAG) = flag;
            const u16** tab = (const u16**)((char*)ws + WS_TAB);
            char* base = (char*)ws + WS_COPY;
            long long cum = 0;
            for (int a = 0; a < 18; ++a) {
                tab[a] = flag ? (const u16*)(base + cum * 2) : (const u16*)orig[a];
                cum += G_SZ[a];
            }
        }
        int* lens = (int*)((char*)ws + WS_LENS);
#pragma unroll 4
        for (int n = tid; n < NUTT; n += 256) {
            int b = n >> 5;
            int u = n & (UU - 1);
            int L = utt_len[d_ids[b] * UU + u];
            lens[n] = min(max(L, 1), TLEN);
        }
    }

    if (flag == 0) return;
    const void* orig[18] = {a0,a1,a2,a3,a4,a5,a6,a7,a8,a9,a10,a11,a12,a13,a14,a15,a16,a17};
    u16* base = (u16*)((char*)ws + WS_COPY);
    const int gtid = blockIdx.x * blockDim.x + tid;
    const int gs   = gridDim.x * blockDim.x;
    long long cum = 0;
    for (int a = 0; a < 18; ++a) {
        const float4* src = (const float4*)orig[a];
        uint2* dst = (uint2*)(base + cum);
        const int n4 = G_SZ[a] >> 2;
        for (int i = gtid; i < n4; i += gs) {
            float4 v = src[i];
            uint2 pk;
            pk.x = (u32)f2b(v.x) | ((u32)f2b(v.y) << 16);
            pk.y = (u32)f2b(v.z) | ((u32)f2b(v.w) << 16);
            dst[i] = pk;
        }
        cum += G_SZ[a];
    }
}

// -------------------------------------------------------------------------
// k_scan: GRU scan, row-half-packed MFMAs (R2, confirmed −49us) plus:
//   accx(i+1) MFMAs split 12+12 into BOTH substeps of iter i (phase
//   overlap: matrix pipe chews x-gates while VALU does gate math).
//   emb staged 2 iters ahead -> 4 emb buffers (2 pairs). Total MFMA
//   issue UNCHANGED vs R2. accx results overwrite dead accx regs.
//   Barrier audit: pre-loop pair0 reads < barrier A(iter0) < pair0
//   restage; each pair restage >= 1 barrier after its last read.
// lane^32 exchange = __shfl_xor (R2-proven; permlane attempts failed).
// Kept: sh_tok pad 132, early-exit tmax, zero-init h, hi/lo split.
// Do NOT cap occupancy via launch_bounds min-waves (weight eviction).
// LDS = 64928 B/block (<= 64 KiB).
// -------------------------------------------------------------------------
__global__ __launch_bounds__(512)
void k_scan(const int* __restrict__ x, void* ws) {
    const u16* const* tab = (const u16* const*)((char*)ws + WS_TAB);
    const int dir = blockIdx.y;
    const u16* emb  = tab[0];
    const u16* w_ih = tab[1 + dir * 4];
    const u16* w_hh = tab[2 + dir * 4];
    const u16* b_ih = tab[3 + dir * 4];
    const u16* b_hh = tab[4 + dir * 4];
    u16* outp = (u16*)((char*)ws + (dir ? WS_OB : WS_OF));
    const int* lens = (const int*)((char*)ws + WS_LENS);

    const int n0 = blockIdx.x * NBU;
    __shared__ __align__(16) u16 sh_emb[4][NBU][264];   // [pair*2+parity][utt][E]
    __shared__ __align__(16) u16 sh_hi[2][NBU * 136];
    __shared__ __align__(16) u16 sh_lo[2][NBU * 136];
    __shared__ __align__(16) u16 sh_out[2][NBU * 1096];
    __shared__ int sh_tok[NBU * 132];
    __shared__ int sh_L[NBU];

    const int tid = threadIdx.x, lane = tid & 63, wvi = tid >> 6;
    const int q4 = lane >> 4, mm = lane & 15;
    const int j = wvi * 16 + mm;
    const int u8 = mm & 7;
    const int arr0 = (q4 & 2);
    const bool a2 = (arr0 != 0);
    const bool lo32 = (lane < 32);

    for (int i = tid; i < NBU * 136; i += 512) { sh_hi[0][i] = 0; sh_lo[0][i] = 0; }
    for (int i = tid; i < NBU * TLEN; i += 512) {
        const int u = i >> 7, tt = i & 127;
        sh_tok[u * 132 + tt] = x[(n0 + u) * TLEN + tt];
    }
    if (tid < NBU) sh_L[tid] = lens[n0 + tid];

    bf16x8 wih[3][8]; bf16x8 whh[3][4];
    float bcr, bcz, bxn, bgn;
#pragma unroll
    for (int n3 = 0; n3 < 3; ++n3) {
        const int g = n3 * HDIM + j;
#pragma unroll
        for (int ks = 0; ks < 8; ++ks)
            wih[n3][ks] = *(const bf16x8*)(w_ih + g * EDIM + ks * 32 + q4 * 8);
#pragma unroll
        for (int ks = 0; ks < 4; ++ks)
            whh[n3][ks] = *(const bf16x8*)(w_hh + g * HDIM + ks * 32 + q4 * 8);
    }
    bcr = b2f(b_ih[j]) + b2f(b_hh[j]);
    bcz = b2f(b_ih[HDIM + j]) + b2f(b_hh[HDIM + j]);
    bxn = b2f(b_ih[2 * HDIM + j]);
    bgn = b2f(b_hh[2 * HDIM + j]);

    float hprev[2] = {0.f, 0.f};
    const f32x4 zero4 = {0.f, 0.f, 0.f, 0.f};
    __syncthreads();

    // block-uniform early-exit bound (multiple of 8)
    int Lm = sh_L[0];
#pragma unroll
    for (int u = 1; u < NBU; ++u) Lm = max(Lm, sh_L[u]);
    const int tmax = (Lm + 7) & ~7;

    // staging map: all 8 waves; group g=wvi>>2 stages parity-g buffers
    const int pf_u = lane & 7;
    const int pf_c = (wvi & 3) * 8 + (lane >> 3);   // 0..31 (E/8 chunks)
    const int pf_L = sh_L[pf_u];
    const int tsel = wvi >> 2;                       // buffer parity this wave stages

    {   // prologue: stage pair0 <- emb[0],emb[1]; pair1 <- emb[2],emb[3]
#pragma unroll
        for (int pp = 0; pp < 2; ++pp) {
            const int tt = 2 * pp + tsel;
            const int te = dir ? max(pf_L - 1 - tt, 0) : tt;
            const int tok = sh_tok[pf_u * 132 + te];
            uint4 v = *(const uint4*)(emb + (size_t)tok * EDIM + pf_c * 8);
            *(uint4*)&sh_emb[pp * 2 + tsel][pf_u][pf_c * 8] = v;
        }
    }
    __syncthreads();

    // accx for iter 0 (t=0,1) from pair0: rows 0-7 = emb[0], 8-15 = emb[1]
    f32x4 accx[3];
    {
        const u16* eb_ = (mm < 8) ? &sh_emb[0][u8][0] : &sh_emb[1][u8][0];
        bf16x8 a = *(const bf16x8*)(eb_ + q4 * 8);
        accx[0] = MFMA16(a, wih[0][0], zero4);
        accx[1] = MFMA16(a, wih[1][0], zero4);
        accx[2] = MFMA16(a, wih[2][0], zero4);
#pragma unroll
        for (int ks = 1; ks < 8; ++ks) {
            bf16x8 av = *(const bf16x8*)(eb_ + ks * 32 + q4 * 8);
            accx[0] = MFMA16(av, wih[0][ks], accx[0]);
            accx[1] = MFMA16(av, wih[1][ks], accx[1]);
            accx[2] = MFMA16(av, wih[2][ks], accx[2]);
        }
    }
    // no extra barrier: iter-0 staging writes pair0 only after barrier A

    for (int t0 = 0; t0 < tmax; t0 += 2) {
        const int pr  = (t0 >> 1) & 1;   // restage target (dead pair)
        const int prn = pr ^ 1;          // pair holding emb for iter i+1
        const int obuf = (t0 >> 3) & 1, slot = t0 & 7;
        const bool morex = (t0 + 2 < tmax);   // compute accx(i+1)?
        const bool stg   = (t0 + 4 < tmax);   // stage pair for iter i+2?

        uint4 pf;
        if (stg) {   // issue early: latency hidden under the whole iter
            const int tt = t0 + 4 + tsel;
            const int te = dir ? max(pf_L - 1 - tt, 0) : tt;
            const int tok = sh_tok[pf_u * 132 + te];
            pf = *(const uint4*)(emb + (size_t)tok * EDIM + pf_c * 8);
        }

        // redistribute accx (iter i): xA = step t0 values, xB = t0+1
        float xA[3][2], xB[3][2];
#pragma unroll
        for (int g = 0; g < 3; ++g) {
#pragma unroll
            for (int r = 0; r < 2; ++r) {
                const float sv = a2 ? accx[g][r] : accx[g][2 + r];   // send
                const float ov = a2 ? accx[g][2 + r] : accx[g][r];   // own
                const float pv = xor32f(sv);
                xA[g][r] = lo32 ? ov : pv;
                xB[g][r] = lo32 ? pv : ov;
            }
        }

        const u16* ebn = (mm < 8) ? &sh_emb[prn * 2][u8][0]
                                  : &sh_emb[prn * 2 + 1][u8][0];

        // ---- substep t0: h in buf0 -> h out buf1; accx(i+1) ks 0-3 ----
        {
            f32x4 accg[3];
            const u16* hb_ = ((mm < 8) ? sh_hi[0] : sh_lo[0]) + u8 * 136;
            {
                bf16x8 a = *(const bf16x8*)(hb_ + q4 * 8);
                accg[0] = MFMA16(a, whh[0][0], zero4);
                accg[1] = MFMA16(a, whh[1][0], zero4);
                accg[2] = MFMA16(a, whh[2][0], zero4);
            }
#pragma unroll
            for (int ks = 1; ks < 4; ++ks) {
                bf16x8 a = *(const bf16x8*)(hb_ + ks * 32 + q4 * 8);
                accg[0] = MFMA16(a, whh[0][ks], accg[0]);
                accg[1] = MFMA16(a, whh[1][ks], accg[1]);
                accg[2] = MFMA16(a, whh[2][ks], accg[2]);
            }
            if (morex) {   // overlaps the gate VALU below on the MFMA pipe
                bf16x8 a = *(const bf16x8*)(ebn + q4 * 8);
                accx[0] = MFMA16(a, wih[0][0], zero4);
                accx[1] = MFMA16(a, wih[1][0], zero4);
                accx[2] = MFMA16(a, wih[2][0], zero4);
#pragma unroll
                for (int ks = 1; ks < 4; ++ks) {
                    bf16x8 av = *(const bf16x8*)(ebn + ks * 32 + q4 * 8);
                    accx[0] = MFMA16(av, wih[0][ks], accx[0]);
                    accx[1] = MFMA16(av, wih[1][ks], accx[1]);
                    accx[2] = MFMA16(av, wih[2][ks], accx[2]);
                }
            }
#pragma unroll
            for (int r = 0; r < 2; ++r) {
                float gg[3];
#pragma unroll
                for (int g = 0; g < 3; ++g) {
                    const float sv = a2 ? accg[g][r] : accg[g][2 + r];
                    const float ov = a2 ? accg[g][2 + r] : accg[g][r];
                    gg[g] = ov + xor32f(sv);   // hi + lo
                }
                const int u = (q4 * 4 + arr0 + r) & 7;
                const float rg = fsigmoid(xA[0][r] + gg[0] + bcr);
                const float zg = fsigmoid(xA[1][r] + gg[1] + bcz);
                const float nn = ftanh((xA[2][r] + bxn) + rg * (gg[2] + bgn));
                const float hn = (1.0f - zg) * nn + zg * hprev[r];
                hprev[r] = hn;
                const u16 hb16 = f2b_hw(hn);
                sh_hi[1][u * 136 + j] = hb16;
                sh_lo[1][u * 136 + j] = f2b_hw(hn - b2f(hb16));
                sh_out[obuf][SOUT(u, slot, j)] = hb16;
            }
        }
        __syncthreads();   // barrier A

        // ---- substep t1: h in buf1 -> h out buf0; accx(i+1) ks 4-7 ----
        {
            f32x4 accg[3];
            const u16* hb_ = ((mm < 8) ? sh_hi[1] : sh_lo[1]) + u8 * 136;
            {
                bf16x8 a = *(const bf16x8*)(hb_ + q4 * 8);
                accg[0] = MFMA16(a, whh[0][0], zero4);
                accg[1] = MFMA16(a, whh[1][0], zero4);
                accg[2] = MFMA16(a, whh[2][0], zero4);
            }
#pragma unroll
            for (int ks = 1; ks < 4; ++ks) {
                bf16x8 a = *(const bf16x8*)(hb_ + ks * 32 + q4 * 8);
                accg[0] = MFMA16(a, whh[0][ks], accg[0]);
                accg[1] = MFMA16(a, whh[1][ks], accg[1]);
                accg[2] = MFMA16(a, whh[2][ks], accg[2]);
            }
            if (morex) {
#pragma unroll
                for (int ks = 4; ks < 8; ++ks) {
                    bf16x8 av = *(const bf16x8*)(ebn + ks * 32 + q4 * 8);
                    accx[0] = MFMA16(av, wih[0][ks], accx[0]);
                    accx[1] = MFMA16(av, wih[1][ks], accx[1]);
                    accx[2] = MFMA16(av, wih[2][ks], accx[2]);
                }
            }
            const int slot1 = slot + 1;
#pragma unroll
            for (int r = 0; r < 2; ++r) {
                float gg[3];
#pragma unroll
                for (int g = 0; g < 3; ++g) {
                    const float sv = a2 ? accg[g][r] : accg[g][2 + r];
                    const float ov = a2 ? accg[g][2 + r] : accg[g][r];
                    gg[g] = ov + xor32f(sv);   // hi + lo
                }
                const int u = (q4 * 4 + arr0 + r) & 7;
                const float rg = fsigmoid(xB[0][r] + gg[0] + bcr);
                const float zg = fsigmoid(xB[1][r] + gg[1] + bcz);
                const float nn = ftanh((xB[2][r] + bxn) + rg * (gg[2] + bgn));
                const float hn = (1.0f - zg) * nn + zg * hprev[r];
                hprev[r] = hn;
                const u16 hb16 = f2b_hw(hn);
                sh_hi[0][u * 136 + j] = hb16;
                sh_lo[0][u * 136 + j] = f2b_hw(hn - b2f(hb16));
                sh_out[obuf][SOUT(u, slot1, j)] = hb16;
            }
        }
        if (stg)   // emb[t0+4+tsel] -> pair pr (dead since iter i-1)
            *(uint4*)&sh_emb[pr * 2 + tsel][pf_u][pf_c * 8] = pf;
        __syncthreads();   // barrier B

        if (((t0 + 1) & 7) == 7) {
            const int rowIdx = tid >> 3;
            const int part   = tid & 7;
            const int fu = rowIdx >> 3, fs = rowIdx & 7;
            const int tt = ((t0 + 1) & ~7) + fs;
            const int tout = dir ? (sh_L[fu] - 1 - tt) : tt;
            if (tout >= 0) {
                const u16* srcp = &sh_out[obuf][SOUT(fu, fs, part * 16)];
                uint4 v0 = *(const uint4*)(srcp);
                uint4 v1 = *(const uint4*)(srcp + 8);
                u16* dstp = outp + ((size_t)(n0 + fu) * TLEN + tout) * HDIM + part * 16;
                *(uint4*)(dstp)     = v0;
                *(uint4*)(dstp + 8) = v1;
            }
        }
    }
}

// -------------------------------------------------------------------------
// k_attn: single-pass per-wave online-softmax attention + epilogue.
// unroll-8 on the latency-exposed Wk^T loop. Score reduce via plain
// __shfl_xor ladder (R2-proven).
// -------------------------------------------------------------------------
__global__ __launch_bounds__(256)
void k_attn(void* ws, void* outv) {
    const u16* const* tab = (const u16* const*)((char*)ws + WS_TAB);
    const u16* wq = tab[9];  const u16* bq = tab[10];
    const u16* wk = tab[11];
    const u16* wv = tab[12]; const u16* bv = tab[13];
    const u16* wo = tab[14]; const u16* bo = tab[15];
    const u16* wl = tab[16]; const u16* bl = tab[17];
    const int* lens = (const int*)((char*)ws + WS_LENS);
    const int flag = *(const int*)((const char*)ws + WS_FLAG);

    const int n = blockIdx.x;
    const int L = lens[n];
    const u16* hf = (const u16*)((char*)ws + WS_OF) + (size_t)n * TLEN * HDIM;
    const u16* hb = (const u16*)((char*)ws + WS_OB) + (size_t)n * TLEN * HDIM;

    __shared__ float sh_hl[EDIM];
    __shared__ float sh_v1[EDIM];
    __shared__ float sh_uv[EDIM];
    __shared__ float sh_a[4 * EDIM];
    __shared__ float sh_m[4], sh_l[4];

    const int tid = threadIdx.x, lane = tid & 63, wid = tid >> 6;

    sh_hl[tid] = (tid < HDIM) ? b2f(hf[(size_t)(L - 1) * HDIM + tid])
                              : b2f(hb[(size_t)(L - 1) * HDIM + (tid - HDIM)]);
    __syncthreads();

    {   // q = Wq h_last + bq
        float s0 = b2f(bq[tid]), s1 = 0.0f;
        const u16* wr = wq + tid * EDIM;
#pragma unroll
        for (int ks = 0; ks < 32; ks += 2) {
            bf16x8 w8 = *(const bf16x8*)(wr + ks * 8);
            bf16x8 w9 = *(const bf16x8*)(wr + ks * 8 + 8);
#pragma unroll
            for (int d = 0; d < 8; ++d) {
                s0 += b2f((u16)w8[d]) * sh_hl[ks * 8 + d];
                s1 += b2f((u16)w9[d]) * sh_hl[ks * 8 + 8 + d];
            }
        }
        sh_v1[tid] = s0 + s1;
    }
    __syncthreads();

    {   // uv = Wk^T q
        float s0 = 0.0f, s1 = 0.0f;
#pragma unroll 8
        for (int i = 0; i < EDIM; i += 2) {
            s0 += b2f(wk[i * EDIM + tid]) * sh_v1[i];
            s1 += b2f(wk[(i + 1) * EDIM + tid]) * sh_v1[i + 1];
        }
        sh_uv[tid] = s0 + s1;
    }
    __syncthreads();

    {   // single pass: score + online softmax + weighted acc
        const int e0 = lane * 4;
        const float u0 = sh_uv[e0], u1 = sh_uv[e0 + 1];
        const float u2 = sh_uv[e0 + 2], u3 = sh_uv[e0 + 3];
        float m = -1e30f, l = 0.0f;
        float a0 = 0.f, a1 = 0.f, a2 = 0.f, a3 = 0.f;
        for (int t = wid; t < L; t += 4) {
            const u16* src = (lane < 32) ? (hf + (size_t)t * HDIM + lane * 4)
                                         : (hb + (size_t)t * HDIM + (lane - 32) * 4);
            uint2 pv = *(const uint2*)src;
            const float h0 = b2f((u16)(pv.x & 0xFFFF));
            const float h1 = b2f((u16)(pv.x >> 16));
            const float h2 = b2f((u16)(pv.y & 0xFFFF));
            const float h3 = b2f((u16)(pv.y >> 16));
            float p = h0 * u0 + h1 * u1 + h2 * u2 + h3 * u3;
#pragma unroll
            for (int o = 32; o > 0; o >>= 1) p += __shfl_xor(p, o);
            const float s = p * 0.0625f;
            const float mn = fmaxf(m, s);
            const float c = __expf(m - mn);
            const float w = __expf(s - mn);
            l = l * c + w;
            a0 = a0 * c + w * h0;
            a1 = a1 * c + w * h1;
            a2 = a2 * c + w * h2;
            a3 = a3 * c + w * h3;
            m = mn;
        }
        sh_a[wid * EDIM + e0]     = a0;
        sh_a[wid * EDIM + e0 + 1] = a1;
        sh_a[wid * EDIM + e0 + 2] = a2;
        sh_a[wid * EDIM + e0 + 3] = a3;
        if (lane == 0) { sh_m[wid] = m; sh_l[wid] = l; }
    }
    __syncthreads();

    {   // merge 4 waves
        const float m0 = sh_m[0], m1 = sh_m[1], m2 = sh_m[2], m3 = sh_m[3];
        const float M = fmaxf(fmaxf(m0, m1), fmaxf(m2, m3));
        const float c0 = __expf(m0 - M), c1 = __expf(m1 - M);
        const float c2 = __expf(m2 - M), c3 = __expf(m3 - M);
        const float den = c0 * sh_l[0] + c1 * sh_l[1] + c2 * sh_l[2] + c3 * sh_l[3];
        const float num = c0 * sh_a[tid] + c1 * sh_a[EDIM + tid] +
                          c2 * sh_a[2 * EDIM + tid] + c3 * sh_a[3 * EDIM + tid];
        sh_hl[tid] = num / den;
    }
    __syncthreads();

    {   // Wv
        float s0 = b2f(bv[tid]), s1 = 0.0f;
        const u16* wr = wv + tid * EDIM;
#pragma unroll
        for (int ks = 0; ks < 32; ks += 2) {
            bf16x8 w8 = *(const bf16x8*)(wr + ks * 8);
            bf16x8 w9 = *(const bf16x8*)(wr + ks * 8 + 8);
#pragma unroll
            for (int d = 0; d < 8; ++d) {
                s0 += b2f((u16)w8[d]) * sh_hl[ks * 8 + d];
                s1 += b2f((u16)w9[d]) * sh_hl[ks * 8 + 8 + d];
            }
        }
        sh_uv[tid] = s0 + s1;
    }
    __syncthreads();

    {   // Wo
        float s0 = b2f(bo[tid]), s1 = 0.0f;
        const u16* wr = wo + tid * EDIM;
#pragma unroll
        for (int ks = 0; ks < 32; ks += 2) {
            bf16x8 w8 = *(const bf16x8*)(wr + ks * 8);
            bf16x8 w9 = *(const bf16x8*)(wr + ks * 8 + 8);
#pragma unroll
            for (int d = 0; d < 8; ++d) {
                s0 += b2f((u16)w8[d]) * sh_uv[ks * 8 + d];
                s1 += b2f((u16)w9[d]) * sh_uv[ks * 8 + 8 + d];
            }
        }
        sh_v1[tid] = s0 + s1;
    }
    __syncthreads();

    {   // Wl -> out
        float s0 = b2f(bl[tid]), s1 = 0.0f;
        const u16* wr = wl + tid * EDIM;
#pragma unroll
        for (int ks = 0; ks < 32; ks += 2) {
            bf16x8 w8 = *(const bf16x8*)(wr + ks * 8);
            bf16x8 w9 = *(const bf16x8*)(wr + ks * 8 + 8);
#pragma unroll
            for (int d = 0; d < 8; ++d) {
                s0 += b2f((u16)w8[d]) * sh_v1[ks * 8 + d];
                s1 += b2f((u16)w9[d]) * sh_v1[ks * 8 + 8 + d];
            }
        }
        const float s = s0 + s1;
        const size_t oidx = (size_t)n * EDIM + tid;
        if (flag) ((float*)outv)[oidx] = s;
        else      ((u16*)outv)[oidx]   = f2b(s);
    }
}

// -------------------------------------------------------------------------
extern "C" void kernel_launch(void* const* d_in, const int* in_sizes, int n_in,
                              void* d_out, int out_size, void* d_ws, size_t ws_size,
                              hipStream_t stream) {
    const int* x       = (const int*)d_in[0];
    const int* d_ids   = (const int*)d_in[1];
    const int* utt_len = (const int*)d_in[2];
    const void* f_arr[18] = {
        d_in[3],
        d_in[4], d_in[5], d_in[6], d_in[7],
        d_in[8], d_in[9], d_in[10], d_in[11],
        d_in[12], d_in[13],
        d_in[14],
        d_in[16], d_in[17],
        d_in[18], d_in[19],
        d_in[20], d_in[21]
    };

    k_convert<<<512, 256, 0, stream>>>(d_ws, d_ids, utt_len,
        f_arr[0], f_arr[1], f_arr[2], f_arr[3], f_arr[4], f_arr[5], f_arr[6], f_arr[7],
        f_arr[8], f_arr[9], f_arr[10], f_arr[11], f_arr[12], f_arr[13], f_arr[14],
        f_arr[15], f_arr[16], f_arr[17]);

    k_scan<<<dim3(NUTT / NBU, 2), 512, 0, stream>>>(x, d_ws);

    k_attn<<<NUTT, 256, 0, stream>>>(d_ws, d_out);
}

// Round 6
// 350.842 us; speedup vs baseline: 1.0858x; 1.0858x over previous
//
#include <hip/hip_runtime.h>
#include <hip/hip_bf16.h>
#include <math.h>
#include <stdint.h>

typedef unsigned short u16;
typedef unsigned int   u32;
typedef __attribute__((ext_vector_type(8))) short bf16x8;
typedef __attribute__((ext_vector_type(4))) float f32x4;

#define EDIM 256
#define HDIM 128
#define TLEN 128
#define NUTT 1024
#define UU   32
#define NBU  8          // utterances per scan block (256 blocks = 1/CU)

#define WS_FLAG 0
#define WS_LENS 64
#define WS_TAB  4608
#define WS_COPY 8192
#define WS_OF   18874368LL
#define WS_OB   52428800LL

#define MFMA16(a, b, c) __builtin_amdgcn_mfma_f32_16x16x32_bf16((a), (b), (c), 0, 0, 0)
#define SOUT(u, s, j) ((u) * 1096 + (s) * 136 + (j))
// the 5 attention 256x256 matrices stored TILED in workspace (always)
#define IS_TILED(a) ((a)==9||(a)==11||(a)==12||(a)==14||(a)==16)

__constant__ int G_SZ[18] = {7680000, 98304, 49152, 384, 384, 98304, 49152, 384, 384,
                             65536, 256, 65536, 65536, 256, 65536, 256, 65536, 256};

__device__ __forceinline__ float b2f(u16 b) {
    u32 u = ((u32)b) << 16; float f; __builtin_memcpy(&f, &u, 4); return f;
}
__device__ __forceinline__ u16 f2b(float f) {   // RNE manual (cold paths)
    u32 u; __builtin_memcpy(&u, &f, 4);
    u32 r = u + 0x7FFFu + ((u >> 16) & 1u);
    return (u16)(r >> 16);
}
__device__ __forceinline__ u16 f2b_hw(float f) {
    __hip_bfloat16 h = __float2bfloat16(f);
    u16 v; __builtin_memcpy(&v, &h, 2); return v;
}
__device__ __forceinline__ float fsigmoid(float x) { return 1.0f / (1.0f + __expf(-x)); }
__device__ __forceinline__ float ftanh(float x) { return 1.0f - 2.0f / (__expf(2.0f * x) + 1.0f); }

// -------------------------------------------------------------------------
// k_convert: detect dtype + build tab + lens + convert. NEW: the five
// attention matrices (wq,wk,wv,wo,wl) are ALWAYS written to workspace in
// an 8-wide tiled layout  dst[(k>>3)*2048 + t*8 + (k&7)]  where t is the
// thread-indexed dim and k the reduction dim (wk is tiled from its
// transpose: t = wk column). This turns k_attn's matvec loads (previously
// 64 lanes x 64 distinct 64B lines per instruction, stride 512B) into
// lane-consecutive 16B loads. Arithmetic order per thread is unchanged.
// -------------------------------------------------------------------------
__global__ __launch_bounds__(256)
void k_convert(void* ws,
               const int* __restrict__ d_ids, const int* __restrict__ utt_len,
               const void* a0, const void* a1, const void* a2, const void* a3,
               const void* a4, const void* a5, const void* a6, const void* a7,
               const void* a8, const void* a9, const void* a10, const void* a11,
               const void* a12, const void* a13, const void* a14, const void* a15,
               const void* a16, const void* a17) {
    __shared__ int scnt[4];
    const int tid = threadIdx.x, lane = tid & 63, wid = tid >> 6;
    const u16* p = (const u16*)a0;
    int cnt = 0;
#pragma unroll 8
    for (int i = tid; i < 16384; i += 256)
        cnt += ((p[i] & 0x7F80) == 0x7F80) ? 1 : 0;
#pragma unroll
    for (int o = 32; o > 0; o >>= 1) cnt += __shfl_down(cnt, o);
    if (lane == 0) scnt[wid] = cnt;
    __syncthreads();
    const int flag = (scnt[0] + scnt[1] + scnt[2] + scnt[3] > 0) ? 1 : 0;

    const void* orig[18] = {a0,a1,a2,a3,a4,a5,a6,a7,a8,a9,a10,a11,a12,a13,a14,a15,a16,a17};
    u16* base = (u16*)((char*)ws + WS_COPY);

    if (blockIdx.x == 0) {
        if (tid == 0) {
            *(int*)((char*)ws + WS_FLAG) = flag;
            const u16** tab = (const u16**)((char*)ws + WS_TAB);
            long long cum = 0;
            for (int a = 0; a < 18; ++a) {
                // tiled matrices ALWAYS live in workspace (both dtype paths)
                tab[a] = (IS_TILED(a) || flag) ? (const u16*)(base + cum)
                                               : (const u16*)orig[a];
                cum += G_SZ[a];
            }
        }
        int* lens = (int*)((char*)ws + WS_LENS);
#pragma unroll 4
        for (int n = tid; n < NUTT; n += 256) {
            int b = n >> 5;
            int u = n & (UU - 1);
            int L = utt_len[d_ids[b] * UU + u];
            lens[n] = min(max(L, 1), TLEN);
        }
    }

    const int gtid = blockIdx.x * blockDim.x + tid;
    const int gs   = gridDim.x * blockDim.x;

    {   // tiled emit of the 5 matrices (always; src f32 if flag else bf16)
        long long offs[18];
        { long long c = 0; for (int a = 0; a < 18; ++a) { offs[a] = c; c += G_SZ[a]; } }
        const int mats[5] = {9, 11, 12, 14, 16};
        for (int q = gtid; q < 5 * 16384; q += gs) {
            const int mi = q >> 14;           // matrix index 0..4
            const int g  = q & 16383;         // quad index within matrix
            const int a  = mats[mi];
            const int e4 = g * 4;
            const int rowa = e4 >> 8, colb = e4 & 255;   // src row, col (4-aligned)
            u16 e[4];
            if (flag) {
                float4 v = ((const float4*)orig[a])[g];
                e[0] = f2b(v.x); e[1] = f2b(v.y); e[2] = f2b(v.z); e[3] = f2b(v.w);
            } else {
                uint2 v = ((const uint2*)orig[a])[g];
                e[0] = (u16)v.x; e[1] = (u16)(v.x >> 16);
                e[2] = (u16)v.y; e[3] = (u16)(v.y >> 16);
            }
            u16* dst = base + offs[a];
            if (a == 11) {   // wk: k = src row (rowa), t = src col (colb+d)
                u16* dd = dst + (rowa >> 3) * 2048 + colb * 8 + (rowa & 7);
                dd[0] = e[0]; dd[8] = e[1]; dd[16] = e[2]; dd[24] = e[3];
            } else {         // wq/wv/wo/wl: t = src row (rowa), k = colb+d
                u16* dd = dst + (colb >> 3) * 2048 + rowa * 8 + (colb & 7);
                dd[0] = e[0]; dd[1] = e[1]; dd[2] = e[2]; dd[3] = e[3];
            }
        }
    }

    if (flag == 0) return;
    long long cum = 0;
    for (int a = 0; a < 18; ++a) {
        if (IS_TILED(a)) { cum += G_SZ[a]; continue; }   // already emitted tiled
        const float4* src = (const float4*)orig[a];
        uint2* dst = (uint2*)(base + cum);
        const int n4 = G_SZ[a] >> 2;
        for (int i = gtid; i < n4; i += gs) {
            float4 v = src[i];
            uint2 pk;
            pk.x = (u32)f2b(v.x) | ((u32)f2b(v.y) << 16);
            pk.y = (u32)f2b(v.z) | ((u32)f2b(v.w) << 16);
            dst[i] = pk;
        }
        cum += G_SZ[a];
    }
}

// -------------------------------------------------------------------------
// k_scan: EXACT revert to the R2-proven 190us version (row-half-packed
// MFMAs: accg rows 0-7=h_hi / 8-15=h_lo recombined via __shfl_xor(.,32);
// accx rows 0-7=emb[t] / 8-15=emb[t+1], one 24-MFMA pass per 2 steps).
// R5's accx-split pipeline REVERTED (regressed 190->199: intra-wave
// reordering never pays here — only work removal does). Permlane swap
// attempts are dead (R3/R4 correctness failures).
// Kept: sh_tok pad 132, early-exit tmax, zero-init h, hi/lo split.
// Do NOT cap occupancy via launch_bounds min-waves (weight eviction).
// -------------------------------------------------------------------------
__global__ __launch_bounds__(512)
void k_scan(const int* __restrict__ x, void* ws) {
    const u16* const* tab = (const u16* const*)((char*)ws + WS_TAB);
    const int dir = blockIdx.y;
    const u16* emb  = tab[0];
    const u16* w_ih = tab[1 + dir * 4];
    const u16* w_hh = tab[2 + dir * 4];
    const u16* b_ih = tab[3 + dir * 4];
    const u16* b_hh = tab[4 + dir * 4];
    u16* outp = (u16*)((char*)ws + (dir ? WS_OB : WS_OF));
    const int* lens = (const int*)((char*)ws + WS_LENS);

    const int n0 = blockIdx.x * NBU;
    __shared__ __align__(16) u16 sh_emb[2][NBU][264];   // [parity of t][utt][E]
    __shared__ __align__(16) u16 sh_hi[2][NBU * 136];
    __shared__ __align__(16) u16 sh_lo[2][NBU * 136];
    __shared__ __align__(16) u16 sh_out[2][NBU * 1096];
    __shared__ int sh_tok[NBU * 132];
    __shared__ int sh_L[NBU];

    const int tid = threadIdx.x, lane = tid & 63, wvi = tid >> 6;
    const int q4 = lane >> 4, mm = lane & 15;
    const int j = wvi * 16 + mm;
    const int u8 = mm & 7;
    const int arr0 = (q4 & 2);
    const bool a2 = (arr0 != 0);
    const bool lo32 = (lane < 32);

    for (int i = tid; i < NBU * 136; i += 512) { sh_hi[0][i] = 0; sh_lo[0][i] = 0; }
    for (int i = tid; i < NBU * TLEN; i += 512) {
        const int u = i >> 7, tt = i & 127;
        sh_tok[u * 132 + tt] = x[(n0 + u) * TLEN + tt];
    }
    if (tid < NBU) sh_L[tid] = lens[n0 + tid];

    bf16x8 wih[3][8]; bf16x8 whh[3][4];
    float bcr, bcz, bxn, bgn;
#pragma unroll
    for (int n3 = 0; n3 < 3; ++n3) {
        const int g = n3 * HDIM + j;
#pragma unroll
        for (int ks = 0; ks < 8; ++ks)
            wih[n3][ks] = *(const bf16x8*)(w_ih + g * EDIM + ks * 32 + q4 * 8);
#pragma unroll
        for (int ks = 0; ks < 4; ++ks)
            whh[n3][ks] = *(const bf16x8*)(w_hh + g * HDIM + ks * 32 + q4 * 8);
    }
    bcr = b2f(b_ih[j]) + b2f(b_hh[j]);
    bcz = b2f(b_ih[HDIM + j]) + b2f(b_hh[HDIM + j]);
    bxn = b2f(b_ih[2 * HDIM + j]);
    bgn = b2f(b_hh[2 * HDIM + j]);

    float hprev[2] = {0.f, 0.f};
    const f32x4 zero4 = {0.f, 0.f, 0.f, 0.f};
    __syncthreads();

    // block-uniform early-exit bound (multiple of 8, hence even)
    int Lm = sh_L[0];
#pragma unroll
    for (int u = 1; u < NBU; ++u) Lm = max(Lm, sh_L[u]);
    const int tmax = (Lm + 7) & ~7;

    // prefetch mapping: ALL 8 waves; waves 0-3 stage even t, waves 4-7 odd t
    const int pf_u = lane & 7;
    const int pf_c = (wvi & 3) * 8 + (lane >> 3);   // 0..31 (E/8 chunks)
    const int pf_L = sh_L[pf_u];
    const int tsel = wvi >> 2;                       // 0: even buf, 1: odd buf

    {   // prologue: stage emb[0] -> buf0, emb[1] -> buf1
        const int te = dir ? max(pf_L - 1 - tsel, 0) : tsel;
        const int tok = sh_tok[pf_u * 132 + te];
        uint4 v = *(const uint4*)(emb + (size_t)tok * EDIM + pf_c * 8);
        *(uint4*)&sh_emb[tsel][pf_u][pf_c * 8] = v;
    }
    __syncthreads();

    for (int t0 = 0; t0 < tmax; t0 += 2) {
        const int obuf = (t0 >> 3) & 1;
        const bool more = (t0 + 2 < tmax);

        uint4 pf;
        if (more) {   // issue early: latency hidden under the whole iter
            const int tt = t0 + 2 + tsel;
            const int te = dir ? max(pf_L - 1 - tt, 0) : tt;
            const int tok = sh_tok[pf_u * 132 + te];
            pf = *(const uint4*)(emb + (size_t)tok * EDIM + pf_c * 8);
        }

        // paired x-gates: A rows 0-7 = emb[t0], rows 8-15 = emb[t0+1]
        f32x4 accx[3];
        {
            const u16* eb_ = (mm < 8) ? &sh_emb[0][u8][0] : &sh_emb[1][u8][0];
            bf16x8 a = *(const bf16x8*)(eb_ + q4 * 8);
            accx[0] = MFMA16(a, wih[0][0], zero4);
            accx[1] = MFMA16(a, wih[1][0], zero4);
            accx[2] = MFMA16(a, wih[2][0], zero4);
#pragma unroll
            for (int ks = 1; ks < 8; ++ks) {
                bf16x8 av = *(const bf16x8*)(eb_ + ks * 32 + q4 * 8);
                accx[0] = MFMA16(av, wih[0][ks], accx[0]);
                accx[1] = MFMA16(av, wih[1][ks], accx[1]);
                accx[2] = MFMA16(av, wih[2][ks], accx[2]);
            }
        }
        // redistribute: xA = this lane's step-t0 values, xB = step-t0+1
        float xA[3][2], xB[3][2];
#pragma unroll
        for (int g = 0; g < 3; ++g) {
#pragma unroll
            for (int r = 0; r < 2; ++r) {
                const float sv = a2 ? accx[g][r] : accx[g][2 + r];   // send
                const float ov = a2 ? accx[g][2 + r] : accx[g][r];   // own
                const float pv = __shfl_xor(sv, 32);
                xA[g][r] = lo32 ? ov : pv;
                xB[g][r] = lo32 ? pv : ov;
            }
        }

        // ---- substep t0: h in buf0 -> h out buf1 ----
        {
            f32x4 accg[3];
            const u16* hb_ = ((mm < 8) ? sh_hi[0] : sh_lo[0]) + u8 * 136;
            {
                bf16x8 a = *(const bf16x8*)(hb_ + q4 * 8);
                accg[0] = MFMA16(a, whh[0][0], zero4);
                accg[1] = MFMA16(a, whh[1][0], zero4);
                accg[2] = MFMA16(a, whh[2][0], zero4);
            }
#pragma unroll
            for (int ks = 1; ks < 4; ++ks) {
                bf16x8 a = *(const bf16x8*)(hb_ + ks * 32 + q4 * 8);
                accg[0] = MFMA16(a, whh[0][ks], accg[0]);
                accg[1] = MFMA16(a, whh[1][ks], accg[1]);
                accg[2] = MFMA16(a, whh[2][ks], accg[2]);
            }
            const int slot = t0 & 7;
#pragma unroll
            for (int r = 0; r < 2; ++r) {
                float gg[3];
#pragma unroll
                for (int g = 0; g < 3; ++g) {
                    const float sv = a2 ? accg[g][r] : accg[g][2 + r];
                    const float ov = a2 ? accg[g][2 + r] : accg[g][r];
                    gg[g] = ov + __shfl_xor(sv, 32);   // hi + lo
                }
                const int u = (q4 * 4 + arr0 + r) & 7;
                const float rg = fsigmoid(xA[0][r] + gg[0] + bcr);
                const float zg = fsigmoid(xA[1][r] + gg[1] + bcz);
                const float nn = ftanh((xA[2][r] + bxn) + rg * (gg[2] + bgn));
                const float hn = (1.0f - zg) * nn + zg * hprev[r];
                hprev[r] = hn;
                const u16 hb16 = f2b_hw(hn);
                sh_hi[1][u * 136 + j] = hb16;
                sh_lo[1][u * 136 + j] = f2b_hw(hn - b2f(hb16));
                sh_out[obuf][SOUT(u, slot, j)] = hb16;
            }
        }
        __syncthreads();   // barrier A

        // ---- substep t1: h in buf1 -> h out buf0 ----
        {
            f32x4 accg[3];
            const u16* hb_ = ((mm < 8) ? sh_hi[1] : sh_lo[1]) + u8 * 136;
            {
                bf16x8 a = *(const bf16x8*)(hb_ + q4 * 8);
                accg[0] = MFMA16(a, whh[0][0], zero4);
                accg[1] = MFMA16(a, whh[1][0], zero4);
                accg[2] = MFMA16(a, whh[2][0], zero4);
            }
#pragma unroll
            for (int ks = 1; ks < 4; ++ks) {
                bf16x8 a = *(const bf16x8*)(hb_ + ks * 32 + q4 * 8);
                accg[0] = MFMA16(a, whh[0][ks], accg[0]);
                accg[1] = MFMA16(a, whh[1][ks], accg[1]);
                accg[2] = MFMA16(a, whh[2][ks], accg[2]);
            }
            const int slot = (t0 & 7) + 1;
#pragma unroll
            for (int r = 0; r < 2; ++r) {
                float gg[3];
#pragma unroll
                for (int g = 0; g < 3; ++g) {
                    const float sv = a2 ? accg[g][r] : accg[g][2 + r];
                    const float ov = a2 ? accg[g][2 + r] : accg[g][r];
                    gg[g] = ov + __shfl_xor(sv, 32);   // hi + lo
                }
                const int u = (q4 * 4 + arr0 + r) & 7;
                const float rg = fsigmoid(xB[0][r] + gg[0] + bcr);
                const float zg = fsigmoid(xB[1][r] + gg[1] + bcz);
                const float nn = ftanh((xB[2][r] + bxn) + rg * (gg[2] + bgn));
                const float hn = (1.0f - zg) * nn + zg * hprev[r];
                hprev[r] = hn;
                const u16 hb16 = f2b_hw(hn);
                sh_hi[0][u * 136 + j] = hb16;
                sh_lo[0][u * 136 + j] = f2b_hw(hn - b2f(hb16));
                sh_out[obuf][SOUT(u, slot, j)] = hb16;
            }
        }
        if (more)   // emb[t0+2]->buf0 (waves 0-3), emb[t0+3]->buf1 (waves 4-7)
            *(uint4*)&sh_emb[tsel][pf_u][pf_c * 8] = pf;
        __syncthreads();   // barrier B

        if (((t0 + 1) & 7) == 7) {
            const int rowIdx = tid >> 3;
            const int part   = tid & 7;
            const int fu = rowIdx >> 3, fs = rowIdx & 7;
            const int tt = ((t0 + 1) & ~7) + fs;
            const int tout = dir ? (sh_L[fu] - 1 - tt) : tt;
            if (tout >= 0) {
                const u16* srcp = &sh_out[obuf][SOUT(fu, fs, part * 16)];
                uint4 v0 = *(const uint4*)(srcp);
                uint4 v1 = *(const uint4*)(srcp + 8);
                u16* dstp = outp + ((size_t)(n0 + fu) * TLEN + tout) * HDIM + part * 16;
                *(uint4*)(dstp)     = v0;
                *(uint4*)(dstp + 8) = v1;
            }
        }
    }
}

// coalesced tiled matvec: out[tid] = bias + sum_k W[t=tid][k]*vin[k].
// wt layout: element (t,k) at wt[(k>>3)*2048 + t*8 + (k&7)] -> the bf16x8
// load below is lane-consecutive 16B (perfect coalescing). Same per-thread
// accumulation order as the old row-major loop (bit-identical results).
__device__ __forceinline__ float matvec_tiled(const u16* __restrict__ wt,
                                              const float* __restrict__ vin,
                                              int tid, float bias) {
    float s0 = bias, s1 = 0.0f;
#pragma unroll
    for (int kt = 0; kt < 32; kt += 2) {
        bf16x8 w8 = *(const bf16x8*)(wt + kt * 2048 + tid * 8);
        bf16x8 w9 = *(const bf16x8*)(wt + (kt + 1) * 2048 + tid * 8);
#pragma unroll
        for (int d = 0; d < 8; ++d) {
            s0 += b2f((u16)w8[d]) * vin[kt * 8 + d];
            s1 += b2f((u16)w9[d]) * vin[kt * 8 + 8 + d];
        }
    }
    return s0 + s1;
}

// -------------------------------------------------------------------------
// k_attn: single-pass per-wave online-softmax attention + epilogue.
// All five 256x256 matvecs now read the TILED weights (coalesced 16B/lane;
// previously 64 distinct 64B lines per load instruction — the theorized
// ~160us TA-serialization sink). wk's tiled form folds its transpose, so
// the uv phase uses the same helper. Math order per thread unchanged.
// -------------------------------------------------------------------------
__global__ __launch_bounds__(256)
void k_attn(void* ws, void* outv) {
    const u16* const* tab = (const u16* const*)((char*)ws + WS_TAB);
    const u16* wq = tab[9];  const u16* bq = tab[10];
    const u16* wk = tab[11];
    const u16* wv = tab[12]; const u16* bv = tab[13];
    const u16* wo = tab[14]; const u16* bo = tab[15];
    const u16* wl = tab[16]; const u16* bl = tab[17];
    const int* lens = (const int*)((char*)ws + WS_LENS);
    const int flag = *(const int*)((const char*)ws + WS_FLAG);

    const int n = blockIdx.x;
    const int L = lens[n];
    const u16* hf = (const u16*)((char*)ws + WS_OF) + (size_t)n * TLEN * HDIM;
    const u16* hb = (const u16*)((char*)ws + WS_OB) + (size_t)n * TLEN * HDIM;

    __shared__ float sh_hl[EDIM];
    __shared__ float sh_v1[EDIM];
    __shared__ float sh_uv[EDIM];
    __shared__ float sh_a[4 * EDIM];
    __shared__ float sh_m[4], sh_l[4];

    const int tid = threadIdx.x, lane = tid & 63, wid = tid >> 6;

    sh_hl[tid] = (tid < HDIM) ? b2f(hf[(size_t)(L - 1) * HDIM + tid])
                              : b2f(hb[(size_t)(L - 1) * HDIM + (tid - HDIM)]);
    __syncthreads();

    // q = Wq h_last + bq
    sh_v1[tid] = matvec_tiled(wq, sh_hl, tid, b2f(bq[tid]));
    __syncthreads();

    // uv = Wk^T q   (wk tiled with t = wk column -> same helper)
    sh_uv[tid] = matvec_tiled(wk, sh_v1, tid, 0.0f);
    __syncthreads();

    {   // single pass: score + online softmax + weighted acc
        const int e0 = lane * 4;
        const float u0 = sh_uv[e0], u1 = sh_uv[e0 + 1];
        const float u2 = sh_uv[e0 + 2], u3 = sh_uv[e0 + 3];
        float m = -1e30f, l = 0.0f;
        float a0 = 0.f, a1 = 0.f, a2 = 0.f, a3 = 0.f;
        for (int t = wid; t < L; t += 4) {
            const u16* src = (lane < 32) ? (hf + (size_t)t * HDIM + lane * 4)
                                         : (hb + (size_t)t * HDIM + (lane - 32) * 4);
            uint2 pv = *(const uint2*)src;
            const float h0 = b2f((u16)(pv.x & 0xFFFF));
            const float h1 = b2f((u16)(pv.x >> 16));
            const float h2 = b2f((u16)(pv.y & 0xFFFF));
            const float h3 = b2f((u16)(pv.y >> 16));
            float p = h0 * u0 + h1 * u1 + h2 * u2 + h3 * u3;
#pragma unroll
            for (int o = 32; o > 0; o >>= 1) p += __shfl_xor(p, o);
            const float s = p * 0.0625f;
            const float mn = fmaxf(m, s);
            const float c = __expf(m - mn);
            const float w = __expf(s - mn);
            l = l * c + w;
            a0 = a0 * c + w * h0;
            a1 = a1 * c + w * h1;
            a2 = a2 * c + w * h2;
            a3 = a3 * c + w * h3;
            m = mn;
        }
        sh_a[wid * EDIM + e0]     = a0;
        sh_a[wid * EDIM + e0 + 1] = a1;
        sh_a[wid * EDIM + e0 + 2] = a2;
        sh_a[wid * EDIM + e0 + 3] = a3;
        if (lane == 0) { sh_m[wid] = m; sh_l[wid] = l; }
    }
    __syncthreads();

    {   // merge 4 waves
        const float m0 = sh_m[0], m1 = sh_m[1], m2 = sh_m[2], m3 = sh_m[3];
        const float M = fmaxf(fmaxf(m0, m1), fmaxf(m2, m3));
        const float c0 = __expf(m0 - M), c1 = __expf(m1 - M);
        const float c2 = __expf(m2 - M), c3 = __expf(m3 - M);
        const float den = c0 * sh_l[0] + c1 * sh_l[1] + c2 * sh_l[2] + c3 * sh_l[3];
        const float num = c0 * sh_a[tid] + c1 * sh_a[EDIM + tid] +
                          c2 * sh_a[2 * EDIM + tid] + c3 * sh_a[3 * EDIM + tid];
        sh_hl[tid] = num / den;
    }
    __syncthreads();

    // ctx -> Wv
    sh_uv[tid] = matvec_tiled(wv, sh_hl, tid, b2f(bv[tid]));
    __syncthreads();

    // Wo
    sh_v1[tid] = matvec_tiled(wo, sh_uv, tid, b2f(bo[tid]));
    __syncthreads();

    // Wl -> out
    {
        const float s = matvec_tiled(wl, sh_v1, tid, b2f(bl[tid]));
        const size_t oidx = (size_t)n * EDIM + tid;
        if (flag) ((float*)outv)[oidx] = s;
        else      ((u16*)outv)[oidx]   = f2b(s);
    }
}

// -------------------------------------------------------------------------
extern "C" void kernel_launch(void* const* d_in, const int* in_sizes, int n_in,
                              void* d_out, int out_size, void* d_ws, size_t ws_size,
                              hipStream_t stream) {
    const int* x       = (const int*)d_in[0];
    const int* d_ids   = (const int*)d_in[1];
    const int* utt_len = (const int*)d_in[2];
    const void* f_arr[18] = {
        d_in[3],
        d_in[4], d_in[5], d_in[6], d_in[7],
        d_in[8], d_in[9], d_in[10], d_in[11],
        d_in[12], d_in[13],
        d_in[14],
        d_in[16], d_in[17],
        d_in[18], d_in[19],
        d_in[20], d_in[21]
    };

    k_convert<<<512, 256, 0, stream>>>(d_ws, d_ids, utt_len,
        f_arr[0], f_arr[1], f_arr[2], f_arr[3], f_arr[4], f_arr[5], f_arr[6], f_arr[7],
        f_arr[8], f_arr[9], f_arr[10], f_arr[11], f_arr[12], f_arr[13], f_arr[14],
        f_arr[15], f_arr[16], f_arr[17]);

    k_scan<<<dim3(NUTT / NBU, 2), 512, 0, stream>>>(x, d_ws);

    k_attn<<<NUTT, 256, 0, stream>>>(d_ws, d_out);
}

// Round 8
// 350.574 us; speedup vs baseline: 1.0866x; 1.0008x over previous
//
#include <hip/hip_runtime.h>
#include <hip/hip_bf16.h>
#include <math.h>
#include <stdint.h>

typedef unsigned short u16;
typedef unsigned int   u32;
typedef __attribute__((ext_vector_type(8))) short bf16x8;
typedef __attribute__((ext_vector_type(4))) float f32x4;

#define EDIM 256
#define HDIM 128
#define TLEN 128
#define NUTT 1024
#define UU   32
#define NBU  8          // utterances per scan block (256 blocks = 1/CU)

#define WS_FLAG 0
#define WS_COPY 8192        // 5 tiled attn matrices, 128 KB each
#define WS_OF   18874368LL
#define WS_OB   52428800LL

#define MFMA16(a, b, c) __builtin_amdgcn_mfma_f32_16x16x32_bf16((a), (b), (c), 0, 0, 0)
#define SOUT(u, s, j) ((u) * 1096 + (s) * 136 + (j))

__device__ __forceinline__ float b2f(u16 b) {
    u32 u = ((u32)b) << 16; float f; __builtin_memcpy(&f, &u, 4); return f;
}
__device__ __forceinline__ u16 f2b(float f) {   // RNE manual (cold paths)
    u32 u; __builtin_memcpy(&u, &f, 4);
    u32 r = u + 0x7FFFu + ((u >> 16) & 1u);
    return (u16)(r >> 16);
}
__device__ __forceinline__ u16 f2b_hw(float f) {
    __hip_bfloat16 h = __float2bfloat16(f);
    u16 v; __builtin_memcpy(&v, &h, 2); return v;
}
__device__ __forceinline__ float fsigmoid(float x) { return 1.0f / (1.0f + __expf(-x)); }
__device__ __forceinline__ float ftanh(float x) { return 1.0f - 2.0f / (__expf(2.0f * x) + 1.0f); }

// flag-aware loaders: consume ORIGINAL input buffers directly.
// flag=1: src is f32, convert (RNE, same rounding as old k_convert copy).
// flag=0: src is bf16, load directly.
__device__ __forceinline__ bf16x8 ldw8(const void* p, size_t off, int flag) {
    if (flag) {
        const float* f = (const float*)p + off;
        float4 a = *(const float4*)f;
        float4 b = *(const float4*)(f + 4);
        union { u16 e[8]; bf16x8 v; } r;
        r.e[0] = f2b_hw(a.x); r.e[1] = f2b_hw(a.y);
        r.e[2] = f2b_hw(a.z); r.e[3] = f2b_hw(a.w);
        r.e[4] = f2b_hw(b.x); r.e[5] = f2b_hw(b.y);
        r.e[6] = f2b_hw(b.z); r.e[7] = f2b_hw(b.w);
        return r.v;
    }
    return *(const bf16x8*)((const u16*)p + off);
}
__device__ __forceinline__ uint4 ldemb(const void* p, size_t off, int flag) {
    if (flag) {
        const float* f = (const float*)p + off;
        float4 a = *(const float4*)f;
        float4 b = *(const float4*)(f + 4);
        uint4 r;
        r.x = (u32)f2b_hw(a.x) | ((u32)f2b_hw(a.y) << 16);
        r.y = (u32)f2b_hw(a.z) | ((u32)f2b_hw(a.w) << 16);
        r.z = (u32)f2b_hw(b.x) | ((u32)f2b_hw(b.y) << 16);
        r.w = (u32)f2b_hw(b.z) | ((u32)f2b_hw(b.w) << 16);
        return r;
    }
    return *(const uint4*)((const u16*)p + off);
}
__device__ __forceinline__ float ldb(const void* p, int i, int flag) {
    return flag ? ((const float*)p)[i] : b2f(((const u16*)p)[i]);
}

// -------------------------------------------------------------------------
// k_convert: SHRUNK (R7). Was converting all 18 arrays (33 MB read, 53 MB
// write) per iteration; k_scan/k_attn now consume original buffers with
// on-the-fly conversion, so this kernel only (a) detects the input dtype
// (same exp-bits scan of emb's first 32 KB, every block locally), and
// (b) emits the five attention matrices tiled:
//   element (t,k) -> dst[(k>>3)*2048 + t*8 + (k&7)]  (wk tiled from its
//   transpose so k_attn's Wk^T matvec uses the same layout).
// ~1.3 MB traffic: launch-overhead-bound, ~6 us.
// -------------------------------------------------------------------------
__global__ __launch_bounds__(256)
void k_convert(void* ws, const void* emb, const void* wq, const void* wk,
               const void* wv, const void* wo, const void* wl) {
    __shared__ int scnt[4];
    const int tid = threadIdx.x, lane = tid & 63, wid = tid >> 6;
    const u16* p = (const u16*)emb;
    int cnt = 0;
#pragma unroll 8
    for (int i = tid; i < 16384; i += 256)
        cnt += ((p[i] & 0x7F80) == 0x7F80) ? 1 : 0;
#pragma unroll
    for (int o = 32; o > 0; o >>= 1) cnt += __shfl_down(cnt, o);
    if (lane == 0) scnt[wid] = cnt;
    __syncthreads();
    const int flag = (scnt[0] + scnt[1] + scnt[2] + scnt[3] > 0) ? 1 : 0;
    if (blockIdx.x == 0 && tid == 0) *(int*)((char*)ws + WS_FLAG) = flag;

    const void* mats[5] = {wq, wk, wv, wo, wl};
    u16* base = (u16*)((char*)ws + WS_COPY);
    const int gtid = blockIdx.x * 256 + tid;
    const int gs   = gridDim.x * 256;
    for (int q = gtid; q < 5 * 16384; q += gs) {
        const int mi = q >> 14;           // matrix index 0..4
        const int g  = q & 16383;         // quad index within matrix
        const int e4 = g * 4;
        const int rowa = e4 >> 8, colb = e4 & 255;   // src row, col (4-aligned)
        u16 e[4];
        if (flag) {
            float4 v = ((const float4*)mats[mi])[g];
            e[0] = f2b(v.x); e[1] = f2b(v.y); e[2] = f2b(v.z); e[3] = f2b(v.w);
        } else {
            uint2 v = ((const uint2*)mats[mi])[g];
            e[0] = (u16)v.x; e[1] = (u16)(v.x >> 16);
            e[2] = (u16)v.y; e[3] = (u16)(v.y >> 16);
        }
        u16* dst = base + mi * 65536;
        if (mi == 1) {   // wk: k = src row (rowa), t = src col (colb+d)
            u16* dd = dst + (rowa >> 3) * 2048 + colb * 8 + (rowa & 7);
            dd[0] = e[0]; dd[8] = e[1]; dd[16] = e[2]; dd[24] = e[3];
        } else {         // wq/wv/wo/wl: t = src row, k = colb+d
            u16* dd = dst + (colb >> 3) * 2048 + rowa * 8 + (colb & 7);
            dd[0] = e[0]; dd[1] = e[1]; dd[2] = e[2]; dd[3] = e[3];
        }
    }
}

// -------------------------------------------------------------------------
// k_scan: R2-proven 190us structure UNCHANGED (row-half-packed MFMAs:
// accg rows 0-7=h_hi/8-15=h_lo, accx rows 0-7=emb[t]/8-15=emb[t+1];
// 24 MFMAs per 2 substeps per wave; 1 barrier/substep). R7 delta is
// plumbing only: weights/biases/emb consumed directly from ORIGINAL
// buffers (flag-aware conversion: weights once at init, emb in the
// prefetch wave, biases exact-f32 when flag=1), and lens computed inline
// from d_ids/utt_len. Failed-and-reverted attempts (do not retry):
// R1/R3/R5 intra-wave reordering (latency-chain-bound at 2 waves/SIMD),
// R3/R4 permlane32_swap (correctness, unverifiable headlessly),
// launch_bounds min-waves cap (weight eviction, FETCH x120).
// -------------------------------------------------------------------------
__global__ __launch_bounds__(512)
void k_scan(const int* __restrict__ x, void* ws,
            const int* __restrict__ d_ids, const int* __restrict__ utt_len,
            const void* embp,
            const void* wihf, const void* whhf, const void* bihf, const void* bhhf,
            const void* wihb, const void* whhb, const void* bihb, const void* bhhb) {
    const int dir = blockIdx.y;
    const void* w_ih = dir ? wihb : wihf;
    const void* w_hh = dir ? whhb : whhf;
    const void* b_ih = dir ? bihb : bihf;
    const void* b_hh = dir ? bhhb : bhhf;
    u16* outp = (u16*)((char*)ws + (dir ? WS_OB : WS_OF));
    const int flag = *(const int*)((const char*)ws + WS_FLAG);

    const int n0 = blockIdx.x * NBU;
    __shared__ __align__(16) u16 sh_emb[2][NBU][264];   // [parity of t][utt][E]
    __shared__ __align__(16) u16 sh_hi[2][NBU * 136];
    __shared__ __align__(16) u16 sh_lo[2][NBU * 136];
    __shared__ __align__(16) u16 sh_out[2][NBU * 1096];
    __shared__ int sh_tok[NBU * 132];
    __shared__ int sh_L[NBU];

    const int tid = threadIdx.x, lane = tid & 63, wvi = tid >> 6;
    const int q4 = lane >> 4, mm = lane & 15;
    const int j = wvi * 16 + mm;
    const int u8 = mm & 7;
    const int arr0 = (q4 & 2);
    const bool a2 = (arr0 != 0);
    const bool lo32 = (lane < 32);

    for (int i = tid; i < NBU * 136; i += 512) { sh_hi[0][i] = 0; sh_lo[0][i] = 0; }
    for (int i = tid; i < NBU * TLEN; i += 512) {
        const int u = i >> 7, tt = i & 127;
        sh_tok[u * 132 + tt] = x[(n0 + u) * TLEN + tt];
    }
    if (tid < NBU) {   // lens inline (was k_convert's WS_LENS table)
        const int gn = n0 + tid;
        const int L = utt_len[d_ids[gn >> 5] * UU + (gn & 31)];
        sh_L[tid] = min(max(L, 1), TLEN);
    }

    bf16x8 wih[3][8]; bf16x8 whh[3][4];
    float bcr, bcz, bxn, bgn;
#pragma unroll
    for (int n3 = 0; n3 < 3; ++n3) {
        const int g = n3 * HDIM + j;
#pragma unroll
        for (int ks = 0; ks < 8; ++ks)
            wih[n3][ks] = ldw8(w_ih, (size_t)g * EDIM + ks * 32 + q4 * 8, flag);
#pragma unroll
        for (int ks = 0; ks < 4; ++ks)
            whh[n3][ks] = ldw8(w_hh, (size_t)g * HDIM + ks * 32 + q4 * 8, flag);
    }
    bcr = ldb(b_ih, j, flag) + ldb(b_hh, j, flag);
    bcz = ldb(b_ih, HDIM + j, flag) + ldb(b_hh, HDIM + j, flag);
    bxn = ldb(b_ih, 2 * HDIM + j, flag);
    bgn = ldb(b_hh, 2 * HDIM + j, flag);

    float hprev[2] = {0.f, 0.f};
    const f32x4 zero4 = {0.f, 0.f, 0.f, 0.f};
    __syncthreads();

    // block-uniform early-exit bound (multiple of 8, hence even)
    int Lm = sh_L[0];
#pragma unroll
    for (int u = 1; u < NBU; ++u) Lm = max(Lm, sh_L[u]);
    const int tmax = (Lm + 7) & ~7;

    // prefetch mapping: ALL 8 waves; waves 0-3 stage even t, waves 4-7 odd t
    const int pf_u = lane & 7;
    const int pf_c = (wvi & 3) * 8 + (lane >> 3);   // 0..31 (E/8 chunks)
    const int pf_L = sh_L[pf_u];
    const int tsel = wvi >> 2;                       // 0: even buf, 1: odd buf

    {   // prologue: stage emb[0] -> buf0, emb[1] -> buf1
        const int te = dir ? max(pf_L - 1 - tsel, 0) : tsel;
        const int tok = sh_tok[pf_u * 132 + te];
        uint4 v = ldemb(embp, (size_t)tok * EDIM + pf_c * 8, flag);
        *(uint4*)&sh_emb[tsel][pf_u][pf_c * 8] = v;
    }
    __syncthreads();

    for (int t0 = 0; t0 < tmax; t0 += 2) {
        const int obuf = (t0 >> 3) & 1;
        const bool more = (t0 + 2 < tmax);

        uint4 pf;
        if (more) {   // issue early: latency hidden under the whole iter
            const int tt = t0 + 2 + tsel;
            const int te = dir ? max(pf_L - 1 - tt, 0) : tt;
            const int tok = sh_tok[pf_u * 132 + te];
            pf = ldemb(embp, (size_t)tok * EDIM + pf_c * 8, flag);
        }

        // paired x-gates: A rows 0-7 = emb[t0], rows 8-15 = emb[t0+1]
        f32x4 accx[3];
        {
            const u16* eb_ = (mm < 8) ? &sh_emb[0][u8][0] : &sh_emb[1][u8][0];
            bf16x8 a = *(const bf16x8*)(eb_ + q4 * 8);
            accx[0] = MFMA16(a, wih[0][0], zero4);
            accx[1] = MFMA16(a, wih[1][0], zero4);
            accx[2] = MFMA16(a, wih[2][0], zero4);
#pragma unroll
            for (int ks = 1; ks < 8; ++ks) {
                bf16x8 av = *(const bf16x8*)(eb_ + ks * 32 + q4 * 8);
                accx[0] = MFMA16(av, wih[0][ks], accx[0]);
                accx[1] = MFMA16(av, wih[1][ks], accx[1]);
                accx[2] = MFMA16(av, wih[2][ks], accx[2]);
            }
        }
        // redistribute: xA = this lane's step-t0 values, xB = step-t0+1
        float xA[3][2], xB[3][2];
#pragma unroll
        for (int g = 0; g < 3; ++g) {
#pragma unroll
            for (int r = 0; r < 2; ++r) {
                const float sv = a2 ? accx[g][r] : accx[g][2 + r];   // send
                const float ov = a2 ? accx[g][2 + r] : accx[g][r];   // own
                const float pv = __shfl_xor(sv, 32);
                xA[g][r] = lo32 ? ov : pv;
                xB[g][r] = lo32 ? pv : ov;
            }
        }

        // ---- substep t0: h in buf0 -> h out buf1 ----
        {
            f32x4 accg[3];
            const u16* hb_ = ((mm < 8) ? sh_hi[0] : sh_lo[0]) + u8 * 136;
            {
                bf16x8 a = *(const bf16x8*)(hb_ + q4 * 8);
                accg[0] = MFMA16(a, whh[0][0], zero4);
                accg[1] = MFMA16(a, whh[1][0], zero4);
                accg[2] = MFMA16(a, whh[2][0], zero4);
            }
#pragma unroll
            for (int ks = 1; ks < 4; ++ks) {
                bf16x8 a = *(const bf16x8*)(hb_ + ks * 32 + q4 * 8);
                accg[0] = MFMA16(a, whh[0][ks], accg[0]);
                accg[1] = MFMA16(a, whh[1][ks], accg[1]);
                accg[2] = MFMA16(a, whh[2][ks], accg[2]);
            }
            const int slot = t0 & 7;
#pragma unroll
            for (int r = 0; r < 2; ++r) {
                float gg[3];
#pragma unroll
                for (int g = 0; g < 3; ++g) {
                    const float sv = a2 ? accg[g][r] : accg[g][2 + r];
                    const float ov = a2 ? accg[g][2 + r] : accg[g][r];
                    gg[g] = ov + __shfl_xor(sv, 32);   // hi + lo
                }
                const int u = (q4 * 4 + arr0 + r) & 7;
                const float rg = fsigmoid(xA[0][r] + gg[0] + bcr);
                const float zg = fsigmoid(xA[1][r] + gg[1] + bcz);
                const float nn = ftanh((xA[2][r] + bxn) + rg * (gg[2] + bgn));
                const float hn = (1.0f - zg) * nn + zg * hprev[r];
                hprev[r] = hn;
                const u16 hb16 = f2b_hw(hn);
                sh_hi[1][u * 136 + j] = hb16;
                sh_lo[1][u * 136 + j] = f2b_hw(hn - b2f(hb16));
                sh_out[obuf][SOUT(u, slot, j)] = hb16;
            }
        }
        __syncthreads();   // barrier A

        // ---- substep t1: h in buf1 -> h out buf0 ----
        {
            f32x4 accg[3];
            const u16* hb_ = ((mm < 8) ? sh_hi[1] : sh_lo[1]) + u8 * 136;
            {
                bf16x8 a = *(const bf16x8*)(hb_ + q4 * 8);
                accg[0] = MFMA16(a, whh[0][0], zero4);
                accg[1] = MFMA16(a, whh[1][0], zero4);
                accg[2] = MFMA16(a, whh[2][0], zero4);
            }
#pragma unroll
            for (int ks = 1; ks < 4; ++ks) {
                bf16x8 a = *(const bf16x8*)(hb_ + ks * 32 + q4 * 8);
                accg[0] = MFMA16(a, whh[0][ks], accg[0]);
                accg[1] = MFMA16(a, whh[1][ks], accg[1]);
                accg[2] = MFMA16(a, whh[2][ks], accg[2]);
            }
            const int slot = (t0 & 7) + 1;
#pragma unroll
            for (int r = 0; r < 2; ++r) {
                float gg[3];
#pragma unroll
                for (int g = 0; g < 3; ++g) {
                    const float sv = a2 ? accg[g][r] : accg[g][2 + r];
                    const float ov = a2 ? accg[g][2 + r] : accg[g][r];
                    gg[g] = ov + __shfl_xor(sv, 32);   // hi + lo
                }
                const int u = (q4 * 4 + arr0 + r) & 7;
                const float rg = fsigmoid(xB[0][r] + gg[0] + bcr);
                const float zg = fsigmoid(xB[1][r] + gg[1] + bcz);
                const float nn = ftanh((xB[2][r] + bxn) + rg * (gg[2] + bgn));
                const float hn = (1.0f - zg) * nn + zg * hprev[r];
                hprev[r] = hn;
                const u16 hb16 = f2b_hw(hn);
                sh_hi[0][u * 136 + j] = hb16;
                sh_lo[0][u * 136 + j] = f2b_hw(hn - b2f(hb16));
                sh_out[obuf][SOUT(u, slot, j)] = hb16;
            }
        }
        if (more)   // emb[t0+2]->buf0 (waves 0-3), emb[t0+3]->buf1 (waves 4-7)
            *(uint4*)&sh_emb[tsel][pf_u][pf_c * 8] = pf;
        __syncthreads();   // barrier B

        if (((t0 + 1) & 7) == 7) {
            const int rowIdx = tid >> 3;
            const int part   = tid & 7;
            const int fu = rowIdx >> 3, fs = rowIdx & 7;
            const int tt = ((t0 + 1) & ~7) + fs;
            const int tout = dir ? (sh_L[fu] - 1 - tt) : tt;
            if (tout >= 0) {
                const u16* srcp = &sh_out[obuf][SOUT(fu, fs, part * 16)];
                uint4 v0 = *(const uint4*)(srcp);
                uint4 v1 = *(const uint4*)(srcp + 8);
                u16* dstp = outp + ((size_t)(n0 + fu) * TLEN + tout) * HDIM + part * 16;
                *(uint4*)(dstp)     = v0;
                *(uint4*)(dstp + 8) = v1;
            }
        }
    }
}

// coalesced tiled matvec: out[tid] = bias + sum_k W[t=tid][k]*vin[k].
// wt layout: element (t,k) at wt[(k>>3)*2048 + t*8 + (k&7)].
__device__ __forceinline__ float matvec_tiled(const u16* __restrict__ wt,
                                              const float* __restrict__ vin,
                                              int tid, float bias) {
    float s0 = bias, s1 = 0.0f;
#pragma unroll
    for (int kt = 0; kt < 32; kt += 2) {
        bf16x8 w8 = *(const bf16x8*)(wt + kt * 2048 + tid * 8);
        bf16x8 w9 = *(const bf16x8*)(wt + (kt + 1) * 2048 + tid * 8);
#pragma unroll
        for (int d = 0; d < 8; ++d) {
            s0 += b2f((u16)w8[d]) * vin[kt * 8 + d];
            s1 += b2f((u16)w9[d]) * vin[kt * 8 + 8 + d];
        }
    }
    return s0 + s1;
}

// -------------------------------------------------------------------------
// k_attn: single-pass per-wave online-softmax attention + epilogue.
// R7: self-sufficient (own L from d_ids/utt_len, biases flag-converted
// from orig); tiled weights at fixed ws offsets. Score loop 2-way
// unrolled: two independent shfl-reduce chains per iteration (ILP), one
// merged online-softmax update (3 exp per 8 rows instead of 4).
// -------------------------------------------------------------------------
__global__ __launch_bounds__(256)
void k_attn(void* ws, void* outv,
            const int* __restrict__ d_ids, const int* __restrict__ utt_len,
            const void* bqp, const void* bvp, const void* bop, const void* blp) {
    const u16* wt = (const u16*)((char*)ws + WS_COPY);
    const u16* wq = wt;
    const u16* wk = wt + 65536;
    const u16* wv = wt + 2 * 65536;
    const u16* wo = wt + 3 * 65536;
    const u16* wl = wt + 4 * 65536;
    const int flag = *(const int*)((const char*)ws + WS_FLAG);

    const int n = blockIdx.x;
    const int L = min(max(utt_len[d_ids[n >> 5] * UU + (n & 31)], 1), TLEN);
    const u16* hf = (const u16*)((char*)ws + WS_OF) + (size_t)n * TLEN * HDIM;
    const u16* hb = (const u16*)((char*)ws + WS_OB) + (size_t)n * TLEN * HDIM;

    __shared__ float sh_hl[EDIM];
    __shared__ float sh_v1[EDIM];
    __shared__ float sh_uv[EDIM];
    __shared__ float sh_a[4 * EDIM];
    __shared__ float sh_m[4], sh_l[4];

    const int tid = threadIdx.x, lane = tid & 63, wid = tid >> 6;

    sh_hl[tid] = (tid < HDIM) ? b2f(hf[(size_t)(L - 1) * HDIM + tid])
                              : b2f(hb[(size_t)(L - 1) * HDIM + (tid - HDIM)]);
    __syncthreads();

    // q = Wq h_last + bq
    sh_v1[tid] = matvec_tiled(wq, sh_hl, tid, ldb(bqp, tid, flag));
    __syncthreads();

    // uv = Wk^T q   (wk tiled with t = wk column; q.bk shift drops in softmax)
    sh_uv[tid] = matvec_tiled(wk, sh_v1, tid, 0.0f);
    __syncthreads();

    {   // single pass: score + online softmax + weighted acc, 2-way unroll
        const int e0 = lane * 4;
        const float u0 = sh_uv[e0], u1 = sh_uv[e0 + 1];
        const float u2 = sh_uv[e0 + 2], u3 = sh_uv[e0 + 3];
        float m = -1e30f, l = 0.0f;
        float a0 = 0.f, a1 = 0.f, a2 = 0.f, a3 = 0.f;
        const size_t lofs = (lane < 32) ? (size_t)(lane * 4)
                                        : (size_t)((lane - 32) * 4);
        const u16* hbase = (lane < 32) ? hf : hb;
        for (int t = wid; t < L; t += 8) {
            const int tB = t + 4;
            const int tBc = (tB < L) ? tB : (L - 1);
            uint2 pvA = *(const uint2*)(hbase + (size_t)t * HDIM + lofs);
            uint2 pvB = *(const uint2*)(hbase + (size_t)tBc * HDIM + lofs);
            const float hA0 = b2f((u16)(pvA.x & 0xFFFF));
            const float hA1 = b2f((u16)(pvA.x >> 16));
            const float hA2 = b2f((u16)(pvA.y & 0xFFFF));
            const float hA3 = b2f((u16)(pvA.y >> 16));
            const float hB0 = b2f((u16)(pvB.x & 0xFFFF));
            const float hB1 = b2f((u16)(pvB.x >> 16));
            const float hB2 = b2f((u16)(pvB.y & 0xFFFF));
            const float hB3 = b2f((u16)(pvB.y >> 16));
            float pA = hA0 * u0 + hA1 * u1 + hA2 * u2 + hA3 * u3;
            float pB = hB0 * u0 + hB1 * u1 + hB2 * u2 + hB3 * u3;
#pragma unroll
            for (int o = 32; o > 0; o >>= 1) {   // two independent chains
                pA += __shfl_xor(pA, o);
                pB += __shfl_xor(pB, o);
            }
            const float sA = pA * 0.0625f;
            const float sB = (tB < L) ? pB * 0.0625f : -1e30f;
            const float mn = fmaxf(m, fmaxf(sA, sB));
            const float c  = __expf(m - mn);
            const float wA = __expf(sA - mn);
            const float wB = __expf(sB - mn);   // underflows to 0 when tB>=L
            l = l * c + wA + wB;
            a0 = a0 * c + wA * hA0 + wB * hB0;
            a1 = a1 * c + wA * hA1 + wB * hB1;
            a2 = a2 * c + wA * hA2 + wB * hB2;
            a3 = a3 * c + wA * hA3 + wB * hB3;
            m = mn;
        }
        sh_a[wid * EDIM + e0]     = a0;
        sh_a[wid * EDIM + e0 + 1] = a1;
        sh_a[wid * EDIM + e0 + 2] = a2;
        sh_a[wid * EDIM + e0 + 3] = a3;
        if (lane == 0) { sh_m[wid] = m; sh_l[wid] = l; }
    }
    __syncthreads();

    {   // merge 4 waves
        const float m0 = sh_m[0], m1 = sh_m[1], m2 = sh_m[2], m3 = sh_m[3];
        const float M = fmaxf(fmaxf(m0, m1), fmaxf(m2, m3));
        const float c0 = __expf(m0 - M), c1 = __expf(m1 - M);
        const float c2 = __expf(m2 - M), c3 = __expf(m3 - M);
        const float den = c0 * sh_l[0] + c1 * sh_l[1] + c2 * sh_l[2] + c3 * sh_l[3];
        const float num = c0 * sh_a[tid] + c1 * sh_a[EDIM + tid] +
                          c2 * sh_a[2 * EDIM + tid] + c3 * sh_a[3 * EDIM + tid];
        sh_hl[tid] = num / den;
    }
    __syncthreads();

    // ctx -> Wv
    sh_uv[tid] = matvec_tiled(wv, sh_hl, tid, ldb(bvp, tid, flag));
    __syncthreads();

    // Wo
    sh_v1[tid] = matvec_tiled(wo, sh_uv, tid, ldb(bop, tid, flag));
    __syncthreads();

    // Wl -> out
    {
        const float s = matvec_tiled(wl, sh_v1, tid, ldb(blp, tid, flag));
        const size_t oidx = (size_t)n * EDIM + tid;
        if (flag) ((float*)outv)[oidx] = s;
        else      ((u16*)outv)[oidx]   = f2b(s);
    }
}

// -------------------------------------------------------------------------
extern "C" void kernel_launch(void* const* d_in, const int* in_sizes, int n_in,
                              void* d_out, int out_size, void* d_ws, size_t ws_size,
                              hipStream_t stream) {
    const int* x       = (const int*)d_in[0];
    const int* d_ids   = (const int*)d_in[1];
    const int* utt_len = (const int*)d_in[2];
    // d_in: 3=emb, 4..7=w_ih_f,w_hh_f,b_ih_f,b_hh_f, 8..11=bwd same,
    // 12=wq,13=bq,14=wk,(15=bk unused: constant shift drops in softmax),
    // 16=wv,17=bv,18=wo,19=bo,20=wl,21=bl

    k_convert<<<160, 256, 0, stream>>>(d_ws, d_in[3], d_in[12], d_in[14],
                                       d_in[16], d_in[18], d_in[20]);

    k_scan<<<dim3(NUTT / NBU, 2), 512, 0, stream>>>(
        x, d_ws, d_ids, utt_len, d_in[3],
        d_in[4], d_in[5], d_in[6], d_in[7],
        d_in[8], d_in[9], d_in[10], d_in[11]);

    k_attn<<<NUTT, 256, 0, stream>>>(d_ws, d_out, d_ids, utt_len,
                                     d_in[13], d_in[17], d_in[19], d_in[21]);
}

// Round 9
// 329.230 us; speedup vs baseline: 1.1570x; 1.0648x over previous
//
#include <hip/hip_runtime.h>
#include <hip/hip_bf16.h>
#include <math.h>
#include <stdint.h>

typedef unsigned short u16;
typedef unsigned int   u32;
typedef __attribute__((ext_vector_type(8))) short bf16x8;
typedef __attribute__((ext_vector_type(4))) float f32x4;

#define EDIM 256
#define HDIM 128
#define TLEN 128
#define NUTT 1024
#define UU   32
#define NBU  8          // utterances per scan block (256 blocks = 1/CU)

#define WS_FLAG 0
#define WS_COPY 8192        // 5 tiled attn matrices, 128 KB each (ends 663552)
#define WS_EMB  1048576LL   // bf16 emb copy when flag=1 (15.36 MB, ends < WS_OF)
#define WS_OF   18874368LL
#define WS_OB   52428800LL

#define MFMA16(a, b, c) __builtin_amdgcn_mfma_f32_16x16x32_bf16((a), (b), (c), 0, 0, 0)
#define SOUT(u, s, j) ((u) * 1096 + (s) * 136 + (j))

__device__ __forceinline__ float b2f(u16 b) {
    u32 u = ((u32)b) << 16; float f; __builtin_memcpy(&f, &u, 4); return f;
}
__device__ __forceinline__ u16 f2b(float f) {   // RNE manual (cold paths)
    u32 u; __builtin_memcpy(&u, &f, 4);
    u32 r = u + 0x7FFFu + ((u >> 16) & 1u);
    return (u16)(r >> 16);
}
__device__ __forceinline__ u16 f2b_hw(float f) {
    __hip_bfloat16 h = __float2bfloat16(f);
    u16 v; __builtin_memcpy(&v, &h, 2); return v;
}
__device__ __forceinline__ float fsigmoid(float x) { return 1.0f / (1.0f + __expf(-x)); }
__device__ __forceinline__ float ftanh(float x) { return 1.0f - 2.0f / (__expf(2.0f * x) + 1.0f); }

// flag-aware loaders for ONE-TIME init reads (weights/biases only; the
// per-step emb path reads bf16 directly — R8 proved on-the-fly f32 emb
// conversion in the prefetch costs +46us in k_scan).
__device__ __forceinline__ bf16x8 ldw8(const void* p, size_t off, int flag) {
    if (flag) {
        const float* f = (const float*)p + off;
        float4 a = *(const float4*)f;
        float4 b = *(const float4*)(f + 4);
        union { u16 e[8]; bf16x8 v; } r;
        r.e[0] = f2b_hw(a.x); r.e[1] = f2b_hw(a.y);
        r.e[2] = f2b_hw(a.z); r.e[3] = f2b_hw(a.w);
        r.e[4] = f2b_hw(b.x); r.e[5] = f2b_hw(b.y);
        r.e[6] = f2b_hw(b.z); r.e[7] = f2b_hw(b.w);
        return r.v;
    }
    return *(const bf16x8*)((const u16*)p + off);
}
__device__ __forceinline__ float ldb(const void* p, int i, int flag) {
    return flag ? ((const float*)p)[i] : b2f(((const u16*)p)[i]);
}

// -------------------------------------------------------------------------
// k_convert (R9): detect dtype + tiled emit of the 5 attention matrices +
// (flag=1 only) emb fp32->bf16 copy into WS_EMB. The emb copy restores
// k_scan's proven-190us bf16 uint4 prefetch path (R8's direct-f32 read
// cost +46us there); ~46 MB of streaming traffic here ≈ +8-10us.
// -------------------------------------------------------------------------
__global__ __launch_bounds__(256)
void k_convert(void* ws, const void* emb, const void* wq, const void* wk,
               const void* wv, const void* wo, const void* wl) {
    __shared__ int scnt[4];
    const int tid = threadIdx.x, lane = tid & 63, wid = tid >> 6;
    const u16* p = (const u16*)emb;
    int cnt = 0;
#pragma unroll 8
    for (int i = tid; i < 16384; i += 256)
        cnt += ((p[i] & 0x7F80) == 0x7F80) ? 1 : 0;
#pragma unroll
    for (int o = 32; o > 0; o >>= 1) cnt += __shfl_down(cnt, o);
    if (lane == 0) scnt[wid] = cnt;
    __syncthreads();
    const int flag = (scnt[0] + scnt[1] + scnt[2] + scnt[3] > 0) ? 1 : 0;
    if (blockIdx.x == 0 && tid == 0) *(int*)((char*)ws + WS_FLAG) = flag;

    const void* mats[5] = {wq, wk, wv, wo, wl};
    u16* base = (u16*)((char*)ws + WS_COPY);
    const int gtid = blockIdx.x * 256 + tid;
    const int gs   = gridDim.x * 256;
    for (int q = gtid; q < 5 * 16384; q += gs) {
        const int mi = q >> 14;           // matrix index 0..4
        const int g  = q & 16383;         // quad index within matrix
        const int e4 = g * 4;
        const int rowa = e4 >> 8, colb = e4 & 255;   // src row, col (4-aligned)
        u16 e[4];
        if (flag) {
            float4 v = ((const float4*)mats[mi])[g];
            e[0] = f2b(v.x); e[1] = f2b(v.y); e[2] = f2b(v.z); e[3] = f2b(v.w);
        } else {
            uint2 v = ((const uint2*)mats[mi])[g];
            e[0] = (u16)v.x; e[1] = (u16)(v.x >> 16);
            e[2] = (u16)v.y; e[3] = (u16)(v.y >> 16);
        }
        u16* dst = base + mi * 65536;
        if (mi == 1) {   // wk: k = src row (rowa), t = src col (colb+d)
            u16* dd = dst + (rowa >> 3) * 2048 + colb * 8 + (rowa & 7);
            dd[0] = e[0]; dd[8] = e[1]; dd[16] = e[2]; dd[24] = e[3];
        } else {         // wq/wv/wo/wl: t = src row, k = colb+d
            u16* dd = dst + (colb >> 3) * 2048 + rowa * 8 + (colb & 7);
            dd[0] = e[0]; dd[1] = e[1]; dd[2] = e[2]; dd[3] = e[3];
        }
    }

    if (flag == 0) return;   // bf16 input: k_scan reads orig emb directly
    {   // emb fp32 -> bf16 into WS_EMB (7,680,000 elements)
        const float4* src = (const float4*)emb;
        uint2* dst = (uint2*)((char*)ws + WS_EMB);
        for (int i = gtid; i < 1920000; i += gs) {
            float4 v = src[i];
            uint2 pk;
            pk.x = (u32)f2b(v.x) | ((u32)f2b(v.y) << 16);
            pk.y = (u32)f2b(v.z) | ((u32)f2b(v.w) << 16);
            dst[i] = pk;
        }
    }
}

// -------------------------------------------------------------------------
// k_scan: R2-proven 190us structure, emb path restored to bf16 uint4
// loads (from WS_EMB when flag=1, orig when flag=0 — byte-identical to
// the R6 code path measured 190us). Weights/biases keep the R8 one-time
// flag-aware init; lens inline from d_ids/utt_len.
// Failed-and-reverted (do not retry): R1/R3/R5 intra-wave reordering
// (latency-chain-bound at 2 waves/SIMD), R3/R4 permlane32_swap
// (correctness), launch_bounds min-waves cap (weight eviction), R8
// on-the-fly f32 emb conversion (+46us).
// -------------------------------------------------------------------------
__global__ __launch_bounds__(512)
void k_scan(const int* __restrict__ x, void* ws,
            const int* __restrict__ d_ids, const int* __restrict__ utt_len,
            const void* embp,
            const void* wihf, const void* whhf, const void* bihf, const void* bhhf,
            const void* wihb, const void* whhb, const void* bihb, const void* bhhb) {
    const int dir = blockIdx.y;
    const void* w_ih = dir ? wihb : wihf;
    const void* w_hh = dir ? whhb : whhf;
    const void* b_ih = dir ? bihb : bihf;
    const void* b_hh = dir ? bhhb : bhhf;
    u16* outp = (u16*)((char*)ws + (dir ? WS_OB : WS_OF));
    const int flag = *(const int*)((const char*)ws + WS_FLAG);
    const u16* emb = flag ? (const u16*)((char*)ws + WS_EMB) : (const u16*)embp;

    const int n0 = blockIdx.x * NBU;
    __shared__ __align__(16) u16 sh_emb[2][NBU][264];   // [parity of t][utt][E]
    __shared__ __align__(16) u16 sh_hi[2][NBU * 136];
    __shared__ __align__(16) u16 sh_lo[2][NBU * 136];
    __shared__ __align__(16) u16 sh_out[2][NBU * 1096];
    __shared__ int sh_tok[NBU * 132];
    __shared__ int sh_L[NBU];

    const int tid = threadIdx.x, lane = tid & 63, wvi = tid >> 6;
    const int q4 = lane >> 4, mm = lane & 15;
    const int j = wvi * 16 + mm;
    const int u8 = mm & 7;
    const int arr0 = (q4 & 2);
    const bool a2 = (arr0 != 0);
    const bool lo32 = (lane < 32);

    for (int i = tid; i < NBU * 136; i += 512) { sh_hi[0][i] = 0; sh_lo[0][i] = 0; }
    for (int i = tid; i < NBU * TLEN; i += 512) {
        const int u = i >> 7, tt = i & 127;
        sh_tok[u * 132 + tt] = x[(n0 + u) * TLEN + tt];
    }
    if (tid < NBU) {   // lens inline
        const int gn = n0 + tid;
        const int L = utt_len[d_ids[gn >> 5] * UU + (gn & 31)];
        sh_L[tid] = min(max(L, 1), TLEN);
    }

    bf16x8 wih[3][8]; bf16x8 whh[3][4];
    float bcr, bcz, bxn, bgn;
#pragma unroll
    for (int n3 = 0; n3 < 3; ++n3) {
        const int g = n3 * HDIM + j;
#pragma unroll
        for (int ks = 0; ks < 8; ++ks)
            wih[n3][ks] = ldw8(w_ih, (size_t)g * EDIM + ks * 32 + q4 * 8, flag);
#pragma unroll
        for (int ks = 0; ks < 4; ++ks)
            whh[n3][ks] = ldw8(w_hh, (size_t)g * HDIM + ks * 32 + q4 * 8, flag);
    }
    bcr = ldb(b_ih, j, flag) + ldb(b_hh, j, flag);
    bcz = ldb(b_ih, HDIM + j, flag) + ldb(b_hh, HDIM + j, flag);
    bxn = ldb(b_ih, 2 * HDIM + j, flag);
    bgn = ldb(b_hh, 2 * HDIM + j, flag);

    float hprev[2] = {0.f, 0.f};
    const f32x4 zero4 = {0.f, 0.f, 0.f, 0.f};
    __syncthreads();

    // block-uniform early-exit bound (multiple of 8, hence even)
    int Lm = sh_L[0];
#pragma unroll
    for (int u = 1; u < NBU; ++u) Lm = max(Lm, sh_L[u]);
    const int tmax = (Lm + 7) & ~7;

    // prefetch mapping: ALL 8 waves; waves 0-3 stage even t, waves 4-7 odd t
    const int pf_u = lane & 7;
    const int pf_c = (wvi & 3) * 8 + (lane >> 3);   // 0..31 (E/8 chunks)
    const int pf_L = sh_L[pf_u];
    const int tsel = wvi >> 2;                       // 0: even buf, 1: odd buf

    {   // prologue: stage emb[0] -> buf0, emb[1] -> buf1
        const int te = dir ? max(pf_L - 1 - tsel, 0) : tsel;
        const int tok = sh_tok[pf_u * 132 + te];
        uint4 v = *(const uint4*)(emb + (size_t)tok * EDIM + pf_c * 8);
        *(uint4*)&sh_emb[tsel][pf_u][pf_c * 8] = v;
    }
    __syncthreads();

    for (int t0 = 0; t0 < tmax; t0 += 2) {
        const int obuf = (t0 >> 3) & 1;
        const bool more = (t0 + 2 < tmax);

        uint4 pf;
        if (more) {   // issue early: latency hidden under the whole iter
            const int tt = t0 + 2 + tsel;
            const int te = dir ? max(pf_L - 1 - tt, 0) : tt;
            const int tok = sh_tok[pf_u * 132 + te];
            pf = *(const uint4*)(emb + (size_t)tok * EDIM + pf_c * 8);
        }

        // paired x-gates: A rows 0-7 = emb[t0], rows 8-15 = emb[t0+1]
        f32x4 accx[3];
        {
            const u16* eb_ = (mm < 8) ? &sh_emb[0][u8][0] : &sh_emb[1][u8][0];
            bf16x8 a = *(const bf16x8*)(eb_ + q4 * 8);
            accx[0] = MFMA16(a, wih[0][0], zero4);
            accx[1] = MFMA16(a, wih[1][0], zero4);
            accx[2] = MFMA16(a, wih[2][0], zero4);
#pragma unroll
            for (int ks = 1; ks < 8; ++ks) {
                bf16x8 av = *(const bf16x8*)(eb_ + ks * 32 + q4 * 8);
                accx[0] = MFMA16(av, wih[0][ks], accx[0]);
                accx[1] = MFMA16(av, wih[1][ks], accx[1]);
                accx[2] = MFMA16(av, wih[2][ks], accx[2]);
            }
        }
        // redistribute: xA = this lane's step-t0 values, xB = step-t0+1
        float xA[3][2], xB[3][2];
#pragma unroll
        for (int g = 0; g < 3; ++g) {
#pragma unroll
            for (int r = 0; r < 2; ++r) {
                const float sv = a2 ? accx[g][r] : accx[g][2 + r];   // send
                const float ov = a2 ? accx[g][2 + r] : accx[g][r];   // own
                const float pv = __shfl_xor(sv, 32);
                xA[g][r] = lo32 ? ov : pv;
                xB[g][r] = lo32 ? pv : ov;
            }
        }

        // ---- substep t0: h in buf0 -> h out buf1 ----
        {
            f32x4 accg[3];
            const u16* hb_ = ((mm < 8) ? sh_hi[0] : sh_lo[0]) + u8 * 136;
            {
                bf16x8 a = *(const bf16x8*)(hb_ + q4 * 8);
                accg[0] = MFMA16(a, whh[0][0], zero4);
                accg[1] = MFMA16(a, whh[1][0], zero4);
                accg[2] = MFMA16(a, whh[2][0], zero4);
            }
#pragma unroll
            for (int ks = 1; ks < 4; ++ks) {
                bf16x8 a = *(const bf16x8*)(hb_ + ks * 32 + q4 * 8);
                accg[0] = MFMA16(a, whh[0][ks], accg[0]);
                accg[1] = MFMA16(a, whh[1][ks], accg[1]);
                accg[2] = MFMA16(a, whh[2][ks], accg[2]);
            }
            const int slot = t0 & 7;
#pragma unroll
            for (int r = 0; r < 2; ++r) {
                float gg[3];
#pragma unroll
                for (int g = 0; g < 3; ++g) {
                    const float sv = a2 ? accg[g][r] : accg[g][2 + r];
                    const float ov = a2 ? accg[g][2 + r] : accg[g][r];
                    gg[g] = ov + __shfl_xor(sv, 32);   // hi + lo
                }
                const int u = (q4 * 4 + arr0 + r) & 7;
                const float rg = fsigmoid(xA[0][r] + gg[0] + bcr);
                const float zg = fsigmoid(xA[1][r] + gg[1] + bcz);
                const float nn = ftanh((xA[2][r] + bxn) + rg * (gg[2] + bgn));
                const float hn = (1.0f - zg) * nn + zg * hprev[r];
                hprev[r] = hn;
                const u16 hb16 = f2b_hw(hn);
                sh_hi[1][u * 136 + j] = hb16;
                sh_lo[1][u * 136 + j] = f2b_hw(hn - b2f(hb16));
                sh_out[obuf][SOUT(u, slot, j)] = hb16;
            }
        }
        __syncthreads();   // barrier A

        // ---- substep t1: h in buf1 -> h out buf0 ----
        {
            f32x4 accg[3];
            const u16* hb_ = ((mm < 8) ? sh_hi[1] : sh_lo[1]) + u8 * 136;
            {
                bf16x8 a = *(const bf16x8*)(hb_ + q4 * 8);
                accg[0] = MFMA16(a, whh[0][0], zero4);
                accg[1] = MFMA16(a, whh[1][0], zero4);
                accg[2] = MFMA16(a, whh[2][0], zero4);
            }
#pragma unroll
            for (int ks = 1; ks < 4; ++ks) {
                bf16x8 a = *(const bf16x8*)(hb_ + ks * 32 + q4 * 8);
                accg[0] = MFMA16(a, whh[0][ks], accg[0]);
                accg[1] = MFMA16(a, whh[1][ks], accg[1]);
                accg[2] = MFMA16(a, whh[2][ks], accg[2]);
            }
            const int slot = (t0 & 7) + 1;
#pragma unroll
            for (int r = 0; r < 2; ++r) {
                float gg[3];
#pragma unroll
                for (int g = 0; g < 3; ++g) {
                    const float sv = a2 ? accg[g][r] : accg[g][2 + r];
                    const float ov = a2 ? accg[g][2 + r] : accg[g][r];
                    gg[g] = ov + __shfl_xor(sv, 32);   // hi + lo
                }
                const int u = (q4 * 4 + arr0 + r) & 7;
                const float rg = fsigmoid(xB[0][r] + gg[0] + bcr);
                const float zg = fsigmoid(xB[1][r] + gg[1] + bcz);
                const float nn = ftanh((xB[2][r] + bxn) + rg * (gg[2] + bgn));
                const float hn = (1.0f - zg) * nn + zg * hprev[r];
                hprev[r] = hn;
                const u16 hb16 = f2b_hw(hn);
                sh_hi[0][u * 136 + j] = hb16;
                sh_lo[0][u * 136 + j] = f2b_hw(hn - b2f(hb16));
                sh_out[obuf][SOUT(u, slot, j)] = hb16;
            }
        }
        if (more)   // emb[t0+2]->buf0 (waves 0-3), emb[t0+3]->buf1 (waves 4-7)
            *(uint4*)&sh_emb[tsel][pf_u][pf_c * 8] = pf;
        __syncthreads();   // barrier B

        if (((t0 + 1) & 7) == 7) {
            const int rowIdx = tid >> 3;
            const int part   = tid & 7;
            const int fu = rowIdx >> 3, fs = rowIdx & 7;
            const int tt = ((t0 + 1) & ~7) + fs;
            const int tout = dir ? (sh_L[fu] - 1 - tt) : tt;
            if (tout >= 0) {
                const u16* srcp = &sh_out[obuf][SOUT(fu, fs, part * 16)];
                uint4 v0 = *(const uint4*)(srcp);
                uint4 v1 = *(const uint4*)(srcp + 8);
                u16* dstp = outp + ((size_t)(n0 + fu) * TLEN + tout) * HDIM + part * 16;
                *(uint4*)(dstp)     = v0;
                *(uint4*)(dstp + 8) = v1;
            }
        }
    }
}

// coalesced tiled matvec: out[tid] = bias + sum_k W[t=tid][k]*vin[k].
// wt layout: element (t,k) at wt[(k>>3)*2048 + t*8 + (k&7)].
__device__ __forceinline__ float matvec_tiled(const u16* __restrict__ wt,
                                              const float* __restrict__ vin,
                                              int tid, float bias) {
    float s0 = bias, s1 = 0.0f;
#pragma unroll
    for (int kt = 0; kt < 32; kt += 2) {
        bf16x8 w8 = *(const bf16x8*)(wt + kt * 2048 + tid * 8);
        bf16x8 w9 = *(const bf16x8*)(wt + (kt + 1) * 2048 + tid * 8);
#pragma unroll
        for (int d = 0; d < 8; ++d) {
            s0 += b2f((u16)w8[d]) * vin[kt * 8 + d];
            s1 += b2f((u16)w9[d]) * vin[kt * 8 + 8 + d];
        }
    }
    return s0 + s1;
}

// -------------------------------------------------------------------------
// k_attn: single-pass per-wave online-softmax attention + epilogue.
// Unchanged from R8 (measured good: non-scan floor dropped 160->~114us).
// -------------------------------------------------------------------------
__global__ __launch_bounds__(256)
void k_attn(void* ws, void* outv,
            const int* __restrict__ d_ids, const int* __restrict__ utt_len,
            const void* bqp, const void* bvp, const void* bop, const void* blp) {
    const u16* wt = (const u16*)((char*)ws + WS_COPY);
    const u16* wq = wt;
    const u16* wk = wt + 65536;
    const u16* wv = wt + 2 * 65536;
    const u16* wo = wt + 3 * 65536;
    const u16* wl = wt + 4 * 65536;
    const int flag = *(const int*)((const char*)ws + WS_FLAG);

    const int n = blockIdx.x;
    const int L = min(max(utt_len[d_ids[n >> 5] * UU + (n & 31)], 1), TLEN);
    const u16* hf = (const u16*)((char*)ws + WS_OF) + (size_t)n * TLEN * HDIM;
    const u16* hb = (const u16*)((char*)ws + WS_OB) + (size_t)n * TLEN * HDIM;

    __shared__ float sh_hl[EDIM];
    __shared__ float sh_v1[EDIM];
    __shared__ float sh_uv[EDIM];
    __shared__ float sh_a[4 * EDIM];
    __shared__ float sh_m[4], sh_l[4];

    const int tid = threadIdx.x, lane = tid & 63, wid = tid >> 6;

    sh_hl[tid] = (tid < HDIM) ? b2f(hf[(size_t)(L - 1) * HDIM + tid])
                              : b2f(hb[(size_t)(L - 1) * HDIM + (tid - HDIM)]);
    __syncthreads();

    // q = Wq h_last + bq
    sh_v1[tid] = matvec_tiled(wq, sh_hl, tid, ldb(bqp, tid, flag));
    __syncthreads();

    // uv = Wk^T q   (wk tiled with t = wk column; q.bk shift drops in softmax)
    sh_uv[tid] = matvec_tiled(wk, sh_v1, tid, 0.0f);
    __syncthreads();

    {   // single pass: score + online softmax + weighted acc, 2-way unroll
        const int e0 = lane * 4;
        const float u0 = sh_uv[e0], u1 = sh_uv[e0 + 1];
        const float u2 = sh_uv[e0 + 2], u3 = sh_uv[e0 + 3];
        float m = -1e30f, l = 0.0f;
        float a0 = 0.f, a1 = 0.f, a2 = 0.f, a3 = 0.f;
        const size_t lofs = (lane < 32) ? (size_t)(lane * 4)
                                        : (size_t)((lane - 32) * 4);
        const u16* hbase = (lane < 32) ? hf : hb;
        for (int t = wid; t < L; t += 8) {
            const int tB = t + 4;
            const int tBc = (tB < L) ? tB : (L - 1);
            uint2 pvA = *(const uint2*)(hbase + (size_t)t * HDIM + lofs);
            uint2 pvB = *(const uint2*)(hbase + (size_t)tBc * HDIM + lofs);
            const float hA0 = b2f((u16)(pvA.x & 0xFFFF));
            const float hA1 = b2f((u16)(pvA.x >> 16));
            const float hA2 = b2f((u16)(pvA.y & 0xFFFF));
            const float hA3 = b2f((u16)(pvA.y >> 16));
            const float hB0 = b2f((u16)(pvB.x & 0xFFFF));
            const float hB1 = b2f((u16)(pvB.x >> 16));
            const float hB2 = b2f((u16)(pvB.y & 0xFFFF));
            const float hB3 = b2f((u16)(pvB.y >> 16));
            float pA = hA0 * u0 + hA1 * u1 + hA2 * u2 + hA3 * u3;
            float pB = hB0 * u0 + hB1 * u1 + hB2 * u2 + hB3 * u3;
#pragma unroll
            for (int o = 32; o > 0; o >>= 1) {   // two independent chains
                pA += __shfl_xor(pA, o);
                pB += __shfl_xor(pB, o);
            }
            const float sA = pA * 0.0625f;
            const float sB = (tB < L) ? pB * 0.0625f : -1e30f;
            const float mn = fmaxf(m, fmaxf(sA, sB));
            const float c  = __expf(m - mn);
            const float wA = __expf(sA - mn);
            const float wB = __expf(sB - mn);   // underflows to 0 when tB>=L
            l = l * c + wA + wB;
            a0 = a0 * c + wA * hA0 + wB * hB0;
            a1 = a1 * c + wA * hA1 + wB * hB1;
            a2 = a2 * c + wA * hA2 + wB * hB2;
            a3 = a3 * c + wA * hA3 + wB * hB3;
            m = mn;
        }
        sh_a[wid * EDIM + e0]     = a0;
        sh_a[wid * EDIM + e0 + 1] = a1;
        sh_a[wid * EDIM + e0 + 2] = a2;
        sh_a[wid * EDIM + e0 + 3] = a3;
        if (lane == 0) { sh_m[wid] = m; sh_l[wid] = l; }
    }
    __syncthreads();

    {   // merge 4 waves
        const float m0 = sh_m[0], m1 = sh_m[1], m2 = sh_m[2], m3 = sh_m[3];
        const float M = fmaxf(fmaxf(m0, m1), fmaxf(m2, m3));
        const float c0 = __expf(m0 - M), c1 = __expf(m1 - M);
        const float c2 = __expf(m2 - M), c3 = __expf(m3 - M);
        const float den = c0 * sh_l[0] + c1 * sh_l[1] + c2 * sh_l[2] + c3 * sh_l[3];
        const float num = c0 * sh_a[tid] + c1 * sh_a[EDIM + tid] +
                          c2 * sh_a[2 * EDIM + tid] + c3 * sh_a[3 * EDIM + tid];
        sh_hl[tid] = num / den;
    }
    __syncthreads();

    // ctx -> Wv
    sh_uv[tid] = matvec_tiled(wv, sh_hl, tid, ldb(bvp, tid, flag));
    __syncthreads();

    // Wo
    sh_v1[tid] = matvec_tiled(wo, sh_uv, tid, ldb(bop, tid, flag));
    __syncthreads();

    // Wl -> out
    {
        const float s = matvec_tiled(wl, sh_v1, tid, ldb(blp, tid, flag));
        const size_t oidx = (size_t)n * EDIM + tid;
        if (flag) ((float*)outv)[oidx] = s;
        else      ((u16*)outv)[oidx]   = f2b(s);
    }
}

// -------------------------------------------------------------------------
extern "C" void kernel_launch(void* const* d_in, const int* in_sizes, int n_in,
                              void* d_out, int out_size, void* d_ws, size_t ws_size,
                              hipStream_t stream) {
    const int* x       = (const int*)d_in[0];
    const int* d_ids   = (const int*)d_in[1];
    const int* utt_len = (const int*)d_in[2];
    // d_in: 3=emb, 4..7=w_ih_f,w_hh_f,b_ih_f,b_hh_f, 8..11=bwd same,
    // 12=wq,13=bq,14=wk,(15=bk unused: constant shift drops in softmax),
    // 16=wv,17=bv,18=wo,19=bo,20=wl,21=bl

    k_convert<<<512, 256, 0, stream>>>(d_ws, d_in[3], d_in[12], d_in[14],
                                       d_in[16], d_in[18], d_in[20]);

    k_scan<<<dim3(NUTT / NBU, 2), 512, 0, stream>>>(
        x, d_ws, d_ids, utt_len, d_in[3],
        d_in[4], d_in[5], d_in[6], d_in[7],
        d_in[8], d_in[9], d_in[10], d_in[11]);

    k_attn<<<NUTT, 256, 0, stream>>>(d_ws, d_out, d_ids, utt_len,
                                     d_in[13], d_in[17], d_in[19], d_in[21]);
}